// Round 1
// baseline (826.188 us; speedup 1.0000x reference)
//
#include <hip/hip_runtime.h>
#include <cstdint>
#include <cstddef>

#define GRES 128   // grid resolution (H = W = L)
#define SC   96    // S*C = 6*16 channels

// ---------------------------------------------------------------------------
// Transpose planes [p][sc][y][x] -> [p][y][x][sc] so the 96 channels of one
// texel are contiguous (384 B, 16B-aligned). One block per (p,y) row-slab.
// LDS tile padded to kill bank conflicts on the transposed read.
// ---------------------------------------------------------------------------
__global__ __launch_bounds__(256) void tp_planes(const float* __restrict__ in,
                                                 float* __restrict__ out)
{
    __shared__ float tile[SC][GRES + 1];
    int py = blockIdx.x;            // p*128 + y
    int p  = py >> 7;
    int y  = py & 127;
    const float* src = in + (size_t)p * SC * GRES * GRES + (size_t)y * GRES;
    for (int i = threadIdx.x; i < SC * GRES; i += 256) {
        int sc = i >> 7;            // channel
        int x  = i & 127;
        tile[sc][x] = src[(size_t)sc * (GRES * GRES) + x];   // coalesced rows
    }
    __syncthreads();
    float* dst = out + (size_t)py * GRES * SC;
    for (int i = threadIdx.x; i < SC * GRES; i += 256) {
        int x  = i / SC;
        int sc = i - x * SC;
        dst[i] = tile[sc][x];       // coalesced writes, conflict-free LDS
    }
}

// Transpose lines [p][sc][z] -> [p][z][sc]. Tiny (144 KB).
__global__ __launch_bounds__(256) void tp_lines(const float* __restrict__ in,
                                                float* __restrict__ out)
{
    int i = blockIdx.x * 256 + threadIdx.x;
    if (i >= 3 * GRES * SC) return;
    int p  = i / (GRES * SC);
    int r  = i - p * (GRES * SC);
    int z  = r / SC;
    int sc = r - z * SC;
    out[i] = in[((size_t)p * SC + sc) * GRES + z];
}

__device__ __forceinline__ void axis_setup(float xnv, int& i0, int& i1, float& w)
{
    float f = (xnv + 1.0f) * 0.5f * (float)(GRES - 1);
    f = fminf(fmaxf(f, 0.0f), (float)(GRES - 1));
    float ff = floorf(f);
    i0 = (int)ff;
    i1 = min(i0 + 1, GRES - 1);
    w  = f - ff;
}

// ---------------------------------------------------------------------------
// Main kernel: one thread per point. Transposed layouts.
// ---------------------------------------------------------------------------
__global__ __launch_bounds__(256) void bwcast_fast(
    const float* __restrict__ xyz, const float* __restrict__ vdirs,
    const float* __restrict__ TP, const float* __restrict__ TL,
    const float* __restrict__ aabb, float* __restrict__ out, int N)
{
    int n = blockIdx.x * 256 + threadIdx.x;
    if (n >= N) return;

    float px = xyz[3 * n + 0], py = xyz[3 * n + 1], pz = xyz[3 * n + 2];
    float xn[3];
    xn[0] = (px - aabb[0]) * (2.0f / (aabb[3] - aabb[0])) - 1.0f;
    xn[1] = (py - aabb[1]) * (2.0f / (aabb[4] - aabb[1])) - 1.0f;
    xn[2] = (pz - aabb[2]) * (2.0f / (aabb[5] - aabb[2])) - 1.0f;

    float bw[6] = {0.f, 0.f, 0.f, 0.f, 0.f, 0.f};

    #pragma unroll
    for (int p = 0; p < 3; ++p) {
        constexpr int M0[3] = {0, 0, 1};
        constexpr int M1[3] = {1, 2, 2};
        constexpr int MV[3] = {2, 1, 0};
        int x0, x1, y0, y1, z0, z1;
        float wx, wy, wz;
        axis_setup(xn[M0[p]], x0, x1, wx);
        axis_setup(xn[M1[p]], y0, y1, wy);
        axis_setup(xn[MV[p]], z0, z1, wz);

        const float* c00 = TP + (size_t)((p * GRES + y0) * GRES + x0) * SC;
        const float* c01 = TP + (size_t)((p * GRES + y0) * GRES + x1) * SC;
        const float* c10 = TP + (size_t)((p * GRES + y1) * GRES + x0) * SC;
        const float* c11 = TP + (size_t)((p * GRES + y1) * GRES + x1) * SC;
        const float* l0  = TL + (size_t)(p * GRES + z0) * SC;
        const float* l1  = TL + (size_t)(p * GRES + z1) * SC;

        float w00 = (1.f - wx) * (1.f - wy);
        float w01 = wx * (1.f - wy);
        float w10 = (1.f - wx) * wy;
        float w11 = wx * wy;
        float uz = 1.f - wz;

        #pragma unroll
        for (int sc = 0; sc < SC; sc += 4) {
            float4 f00 = *(const float4*)(c00 + sc);
            float4 f01 = *(const float4*)(c01 + sc);
            float4 f10 = *(const float4*)(c10 + sc);
            float4 f11 = *(const float4*)(c11 + sc);
            float4 g0  = *(const float4*)(l0 + sc);
            float4 g1  = *(const float4*)(l1 + sc);
            const int s = sc >> 4;   // compile-time after unroll -> bw in regs
            float acc = bw[s];
            {
                float pv = fmaf(f00.x, w00, fmaf(f01.x, w01, fmaf(f10.x, w10, f11.x * w11)));
                float lv = fmaf(g0.x, uz, g1.x * wz);
                acc = fmaf(pv, lv, acc);
            }
            {
                float pv = fmaf(f00.y, w00, fmaf(f01.y, w01, fmaf(f10.y, w10, f11.y * w11)));
                float lv = fmaf(g0.y, uz, g1.y * wz);
                acc = fmaf(pv, lv, acc);
            }
            {
                float pv = fmaf(f00.z, w00, fmaf(f01.z, w01, fmaf(f10.z, w10, f11.z * w11)));
                float lv = fmaf(g0.z, uz, g1.z * wz);
                acc = fmaf(pv, lv, acc);
            }
            {
                float pv = fmaf(f00.w, w00, fmaf(f01.w, w01, fmaf(f10.w, w10, f11.w * w11)));
                float lv = fmaf(g0.w, uz, g1.w * wz);
                acc = fmaf(pv, lv, acc);
            }
            bw[s] = acc;
        }
    }

    // ---- Rodrigues / screw transform ----
    float wxr = bw[0], wyr = bw[1], wzr = bw[2];
    float dotw = wxr * wxr + wyr * wyr + wzr * wzr;
    float theta = sqrtf(fmaxf(dotw, 1e-6f));
    float it = 1.0f / theta;
    float ux = wxr * it, uy = wyr * it, un = wzr * it;
    float vx = bw[3] * it, vy = bw[4] * it, vz = bw[5] * it;
    float st, ct;
    sincosf(theta, &st, &ct);
    float q   = ux * ux + uy * uy + un * un;   // == 1 unless theta clipped
    float omc = 1.0f - ct;
    // R = (1 - omc*q) I + st*W + omc*uu^T    (W^2 = uu^T - q I identity)
    float ra = 1.0f - omc * q;
    float R00 = ra + omc * ux * ux;
    float R01 = omc * ux * uy - st * un;
    float R02 = omc * ux * un + st * uy;
    float R10 = omc * uy * ux + st * un;
    float R11 = ra + omc * uy * uy;
    float R12 = omc * uy * un - st * ux;
    float R20 = omc * un * ux - st * uy;
    float R21 = omc * un * uy + st * ux;
    float R22 = ra + omc * un * un;
    // P = (theta - tms*q) I + omc*W + tms*uu^T,  tms = theta - st
    float tms = theta - st;
    float pa  = theta - tms * q;
    float P00 = pa + tms * ux * ux;
    float P01 = tms * ux * uy - omc * un;
    float P02 = tms * ux * un + omc * uy;
    float P10 = tms * uy * ux + omc * un;
    float P11 = pa + tms * uy * uy;
    float P12 = tms * uy * un - omc * ux;
    float P20 = tms * un * ux - omc * uy;
    float P21 = tms * un * uy + omc * ux;
    float P22 = pa + tms * un * un;

    float tx = P00 * vx + P01 * vy + P02 * vz;
    float ty = P10 * vx + P11 * vy + P12 * vz;
    float tz = P20 * vx + P21 * vy + P22 * vz;

    float ox = R00 * px + R01 * py + R02 * pz + tx;
    float oy = R10 * px + R11 * py + R12 * pz + ty;
    float oz = R20 * px + R21 * py + R22 * pz + tz;

    float dx = vdirs[3 * n + 0], dy = vdirs[3 * n + 1], dz = vdirs[3 * n + 2];
    float wvx = R00 * dx + R01 * dy + R02 * dz;
    float wvy = R10 * dx + R11 * dy + R12 * dz;
    float wvz = R20 * dx + R21 * dy + R22 * dz;

    out[3 * n + 0] = ox;
    out[3 * n + 1] = oy;
    out[3 * n + 2] = oz;
    size_t off = (size_t)3 * N;
    out[off + 3 * n + 0] = wvx;
    out[off + 3 * n + 1] = wvy;
    out[off + 3 * n + 2] = wvz;
}

// ---------------------------------------------------------------------------
// Fallback: original layouts (only used if d_ws too small for the transpose).
// ---------------------------------------------------------------------------
__global__ __launch_bounds__(256) void bwcast_direct(
    const float* __restrict__ xyz, const float* __restrict__ vdirs,
    const float* __restrict__ PL, const float* __restrict__ LN,
    const float* __restrict__ aabb, float* __restrict__ out, int N)
{
    int n = blockIdx.x * 256 + threadIdx.x;
    if (n >= N) return;

    float px = xyz[3 * n + 0], py = xyz[3 * n + 1], pz = xyz[3 * n + 2];
    float xn[3];
    xn[0] = (px - aabb[0]) * (2.0f / (aabb[3] - aabb[0])) - 1.0f;
    xn[1] = (py - aabb[1]) * (2.0f / (aabb[4] - aabb[1])) - 1.0f;
    xn[2] = (pz - aabb[2]) * (2.0f / (aabb[5] - aabb[2])) - 1.0f;

    float bw[6] = {0.f, 0.f, 0.f, 0.f, 0.f, 0.f};

    #pragma unroll
    for (int p = 0; p < 3; ++p) {
        constexpr int M0[3] = {0, 0, 1};
        constexpr int M1[3] = {1, 2, 2};
        constexpr int MV[3] = {2, 1, 0};
        int x0, x1, y0, y1, z0, z1;
        float wx, wy, wz;
        axis_setup(xn[M0[p]], x0, x1, wx);
        axis_setup(xn[M1[p]], y0, y1, wy);
        axis_setup(xn[MV[p]], z0, z1, wz);
        float w00 = (1.f - wx) * (1.f - wy);
        float w01 = wx * (1.f - wy);
        float w10 = (1.f - wx) * wy;
        float w11 = wx * wy;
        float uz = 1.f - wz;
        #pragma unroll
        for (int s = 0; s < 6; ++s) {
            float acc = bw[s];
            for (int c = 0; c < 16; ++c) {
                int sc = s * 16 + c;
                const float* pb = PL + (size_t)(p * SC + sc) * (GRES * GRES);
                float f00 = pb[y0 * GRES + x0];
                float f01 = pb[y0 * GRES + x1];
                float f10 = pb[y1 * GRES + x0];
                float f11 = pb[y1 * GRES + x1];
                const float* lb = LN + (size_t)(p * SC + sc) * GRES;
                float lv = fmaf(lb[z0], uz, lb[z1] * wz);
                float pv = fmaf(f00, w00, fmaf(f01, w01, fmaf(f10, w10, f11 * w11)));
                acc = fmaf(pv, lv, acc);
            }
            bw[s] = acc;
        }
    }

    float wxr = bw[0], wyr = bw[1], wzr = bw[2];
    float dotw = wxr * wxr + wyr * wyr + wzr * wzr;
    float theta = sqrtf(fmaxf(dotw, 1e-6f));
    float it = 1.0f / theta;
    float ux = wxr * it, uy = wyr * it, un = wzr * it;
    float vx = bw[3] * it, vy = bw[4] * it, vz = bw[5] * it;
    float st, ct;
    sincosf(theta, &st, &ct);
    float q   = ux * ux + uy * uy + un * un;
    float omc = 1.0f - ct;
    float ra = 1.0f - omc * q;
    float R00 = ra + omc * ux * ux;
    float R01 = omc * ux * uy - st * un;
    float R02 = omc * ux * un + st * uy;
    float R10 = omc * uy * ux + st * un;
    float R11 = ra + omc * uy * uy;
    float R12 = omc * uy * un - st * ux;
    float R20 = omc * un * ux - st * uy;
    float R21 = omc * un * uy + st * ux;
    float R22 = ra + omc * un * un;
    float tms = theta - st;
    float pa  = theta - tms * q;
    float P00 = pa + tms * ux * ux;
    float P01 = tms * ux * uy - omc * un;
    float P02 = tms * ux * un + omc * uy;
    float P10 = tms * uy * ux + omc * un;
    float P11 = pa + tms * uy * uy;
    float P12 = tms * uy * un - omc * ux;
    float P20 = tms * un * ux - omc * uy;
    float P21 = tms * un * uy + omc * ux;
    float P22 = pa + tms * un * un;

    float tx = P00 * vx + P01 * vy + P02 * vz;
    float ty = P10 * vx + P11 * vy + P12 * vz;
    float tz = P20 * vx + P21 * vy + P22 * vz;

    float ox = R00 * px + R01 * py + R02 * pz + tx;
    float oy = R10 * px + R11 * py + R12 * pz + ty;
    float oz = R20 * px + R21 * py + R22 * pz + tz;

    float dx = vdirs[3 * n + 0], dy = vdirs[3 * n + 1], dz = vdirs[3 * n + 2];
    float wvx = R00 * dx + R01 * dy + R02 * dz;
    float wvy = R10 * dx + R11 * dy + R12 * dz;
    float wvz = R20 * dx + R21 * dy + R22 * dz;

    out[3 * n + 0] = ox;
    out[3 * n + 1] = oy;
    out[3 * n + 2] = oz;
    size_t off = (size_t)3 * N;
    out[off + 3 * n + 0] = wvx;
    out[off + 3 * n + 1] = wvy;
    out[off + 3 * n + 2] = wvz;
}

extern "C" void kernel_launch(void* const* d_in, const int* in_sizes, int n_in,
                              void* d_out, int out_size, void* d_ws, size_t ws_size,
                              hipStream_t stream)
{
    const float* xyz    = (const float*)d_in[0];
    const float* vd     = (const float*)d_in[1];
    // d_in[2] = transforms (unused), d_in[3] = ray_valid (unused)
    const float* planes = (const float*)d_in[4];
    const float* lines  = (const float*)d_in[5];
    const float* aabb   = (const float*)d_in[6];
    float* out = (float*)d_out;

    int N = in_sizes[0] / 3;   // 524288

    size_t needP = (size_t)3 * GRES * GRES * SC * sizeof(float);  // 18.87 MB
    size_t needL = (size_t)3 * GRES * SC * sizeof(float);         // 147 KB

    if (ws_size >= needP + needL) {
        float* TP = (float*)d_ws;
        float* TL = TP + (size_t)3 * GRES * GRES * SC;
        tp_planes<<<3 * GRES, 256, 0, stream>>>(planes, TP);
        tp_lines<<<(3 * GRES * SC + 255) / 256, 256, 0, stream>>>(lines, TL);
        bwcast_fast<<<(N + 255) / 256, 256, 0, stream>>>(xyz, vd, TP, TL, aabb, out, N);
    } else {
        bwcast_direct<<<(N + 255) / 256, 256, 0, stream>>>(xyz, vd, planes, lines, aabb, out, N);
    }
}

// Round 2
// 414.210 us; speedup vs baseline: 1.9946x; 1.9946x over previous
//
#include <hip/hip_runtime.h>
#include <cstdint>
#include <cstddef>

#define GRES 128   // grid resolution (H = W = L)
#define SC   96    // S*C = 6*16 channels

// ---------------------------------------------------------------------------
// Transpose planes [p][sc][y][x] -> [p][y][x][sc] so the 96 channels of one
// texel are contiguous (384 B, 16B-aligned). One block per (p,y) row-slab.
// ---------------------------------------------------------------------------
__global__ __launch_bounds__(256) void tp_planes(const float* __restrict__ in,
                                                 float* __restrict__ out)
{
    __shared__ float tile[SC][GRES + 1];
    int py = blockIdx.x;            // p*128 + y
    int p  = py >> 7;
    int y  = py & 127;
    const float* src = in + (size_t)p * SC * GRES * GRES + (size_t)y * GRES;
    for (int i = threadIdx.x; i < SC * GRES; i += 256) {
        int sc = i >> 7;            // channel
        int x  = i & 127;
        tile[sc][x] = src[(size_t)sc * (GRES * GRES) + x];   // coalesced rows
    }
    __syncthreads();
    float* dst = out + (size_t)py * GRES * SC;
    for (int i = threadIdx.x; i < SC * GRES; i += 256) {
        int x  = i / SC;
        int sc = i - x * SC;
        dst[i] = tile[sc][x];       // coalesced writes, conflict-free LDS
    }
}

// Transpose lines [p][sc][z] -> [p][z][sc]. Tiny (144 KB).
__global__ __launch_bounds__(256) void tp_lines(const float* __restrict__ in,
                                                float* __restrict__ out)
{
    int i = blockIdx.x * 256 + threadIdx.x;
    if (i >= 3 * GRES * SC) return;
    int p  = i / (GRES * SC);
    int r  = i - p * (GRES * SC);
    int z  = r / SC;
    int sc = r - z * SC;
    out[i] = in[((size_t)p * SC + sc) * GRES + z];
}

__device__ __forceinline__ void axis_setup(float xnv, int& i0, int& i1, float& w)
{
    float f = (xnv + 1.0f) * 0.5f * (float)(GRES - 1);
    f = fminf(fmaxf(f, 0.0f), (float)(GRES - 1));
    float ff = floorf(f);
    i0 = (int)ff;
    i1 = min(i0 + 1, GRES - 1);
    w  = f - ff;
}

// ---------------------------------------------------------------------------
// Main kernel: FOUR lanes per point. Lane l handles channel chunks
// sc = 16*k + 4*l (k = 0..5), so each lane's k-partial maps to exactly one
// output slot s = k. Cross-lane reduce = 2x shfl_xor. Low VGPR -> high occ.
// ---------------------------------------------------------------------------
__global__ __launch_bounds__(256) void bwcast_fast4(
    const float* __restrict__ xyz, const float* __restrict__ vdirs,
    const float* __restrict__ TP, const float* __restrict__ TL,
    const float* __restrict__ aabb, float* __restrict__ out, int N)
{
    int t = blockIdx.x * 256 + threadIdx.x;
    int n = t >> 2;          // point index
    int l = t & 3;           // sub-lane within point
    if (n >= N) return;

    float px = xyz[3 * n + 0], py = xyz[3 * n + 1], pz = xyz[3 * n + 2];
    float xn[3];
    xn[0] = (px - aabb[0]) * (2.0f / (aabb[3] - aabb[0])) - 1.0f;
    xn[1] = (py - aabb[1]) * (2.0f / (aabb[4] - aabb[1])) - 1.0f;
    xn[2] = (pz - aabb[2]) * (2.0f / (aabb[5] - aabb[2])) - 1.0f;

    float part[6] = {0.f, 0.f, 0.f, 0.f, 0.f, 0.f};
    const int loff = l * 4;  // float offset of this lane's chunk within 16

    #pragma unroll
    for (int p = 0; p < 3; ++p) {
        constexpr int M0[3] = {0, 0, 1};
        constexpr int M1[3] = {1, 2, 2};
        constexpr int MV[3] = {2, 1, 0};
        int x0, x1, y0, y1, z0, z1;
        float wx, wy, wz;
        axis_setup(xn[M0[p]], x0, x1, wx);
        axis_setup(xn[M1[p]], y0, y1, wy);
        axis_setup(xn[MV[p]], z0, z1, wz);

        const float* c00 = TP + (size_t)((p * GRES + y0) * GRES + x0) * SC + loff;
        const float* c01 = TP + (size_t)((p * GRES + y0) * GRES + x1) * SC + loff;
        const float* c10 = TP + (size_t)((p * GRES + y1) * GRES + x0) * SC + loff;
        const float* c11 = TP + (size_t)((p * GRES + y1) * GRES + x1) * SC + loff;
        const float* l0  = TL + (size_t)(p * GRES + z0) * SC + loff;
        const float* l1  = TL + (size_t)(p * GRES + z1) * SC + loff;

        float w00 = (1.f - wx) * (1.f - wy);
        float w01 = wx * (1.f - wy);
        float w10 = (1.f - wx) * wy;
        float w11 = wx * wy;
        float uz = 1.f - wz;

        #pragma unroll
        for (int k = 0; k < 6; ++k) {
            const int sc = k * 16;   // + loff already in base pointers
            float4 f00 = *(const float4*)(c00 + sc);
            float4 f01 = *(const float4*)(c01 + sc);
            float4 f10 = *(const float4*)(c10 + sc);
            float4 f11 = *(const float4*)(c11 + sc);
            float4 g0  = *(const float4*)(l0 + sc);
            float4 g1  = *(const float4*)(l1 + sc);
            float acc = part[k];
            {
                float pv = fmaf(f00.x, w00, fmaf(f01.x, w01, fmaf(f10.x, w10, f11.x * w11)));
                float lv = fmaf(g0.x, uz, g1.x * wz);
                acc = fmaf(pv, lv, acc);
            }
            {
                float pv = fmaf(f00.y, w00, fmaf(f01.y, w01, fmaf(f10.y, w10, f11.y * w11)));
                float lv = fmaf(g0.y, uz, g1.y * wz);
                acc = fmaf(pv, lv, acc);
            }
            {
                float pv = fmaf(f00.z, w00, fmaf(f01.z, w01, fmaf(f10.z, w10, f11.z * w11)));
                float lv = fmaf(g0.z, uz, g1.z * wz);
                acc = fmaf(pv, lv, acc);
            }
            {
                float pv = fmaf(f00.w, w00, fmaf(f01.w, w01, fmaf(f10.w, w10, f11.w * w11)));
                float lv = fmaf(g0.w, uz, g1.w * wz);
                acc = fmaf(pv, lv, acc);
            }
            part[k] = acc;
        }
    }

    // Reduce the 4 lanes' partials (masks 1 and 2 stay within the 4-group).
    float bw[6];
    #pragma unroll
    for (int s = 0; s < 6; ++s) {
        float v = part[s];
        v += __shfl_xor(v, 1);
        v += __shfl_xor(v, 2);
        bw[s] = v;
    }

    // ---- Rodrigues / screw transform (all 4 lanes redundantly) ----
    float wxr = bw[0], wyr = bw[1], wzr = bw[2];
    float dotw = wxr * wxr + wyr * wyr + wzr * wzr;
    float theta = sqrtf(fmaxf(dotw, 1e-6f));
    float it = 1.0f / theta;
    float ux = wxr * it, uy = wyr * it, un = wzr * it;
    float vx = bw[3] * it, vy = bw[4] * it, vz = bw[5] * it;
    float st, ct;
    sincosf(theta, &st, &ct);
    float q   = ux * ux + uy * uy + un * un;   // == 1 unless theta clipped
    float omc = 1.0f - ct;
    float ra = 1.0f - omc * q;                 // skew(u)^2 = uu^T - q I
    float R00 = ra + omc * ux * ux;
    float R01 = omc * ux * uy - st * un;
    float R02 = omc * ux * un + st * uy;
    float R10 = omc * uy * ux + st * un;
    float R11 = ra + omc * uy * uy;
    float R12 = omc * uy * un - st * ux;
    float R20 = omc * un * ux - st * uy;
    float R21 = omc * un * uy + st * ux;
    float R22 = ra + omc * un * un;
    float tms = theta - st;
    float pa  = theta - tms * q;
    float P00 = pa + tms * ux * ux;
    float P01 = tms * ux * uy - omc * un;
    float P02 = tms * ux * un + omc * uy;
    float P10 = tms * uy * ux + omc * un;
    float P11 = pa + tms * uy * uy;
    float P12 = tms * uy * un - omc * ux;
    float P20 = tms * un * ux - omc * uy;
    float P21 = tms * un * uy + omc * ux;
    float P22 = pa + tms * un * un;

    float tx = P00 * vx + P01 * vy + P02 * vz;
    float ty = P10 * vx + P11 * vy + P12 * vz;
    float tz = P20 * vx + P21 * vy + P22 * vz;

    float ox = R00 * px + R01 * py + R02 * pz + tx;
    float oy = R10 * px + R11 * py + R12 * pz + ty;
    float oz = R20 * px + R21 * py + R22 * pz + tz;

    float dx = vdirs[3 * n + 0], dy = vdirs[3 * n + 1], dz = vdirs[3 * n + 2];
    float wvx = R00 * dx + R01 * dy + R02 * dz;
    float wvy = R10 * dx + R11 * dy + R12 * dz;
    float wvz = R20 * dx + R21 * dy + R22 * dz;

    // Lane l < 3 writes component l of both outputs.
    if (l < 3) {
        float o  = (l == 0) ? ox : (l == 1) ? oy : oz;
        float wv = (l == 0) ? wvx : (l == 1) ? wvy : wvz;
        out[3 * n + l] = o;
        out[(size_t)3 * N + 3 * n + l] = wv;
    }
}

// ---------------------------------------------------------------------------
// Fallback: original layouts (only used if d_ws too small for the transpose).
// ---------------------------------------------------------------------------
__global__ __launch_bounds__(256) void bwcast_direct(
    const float* __restrict__ xyz, const float* __restrict__ vdirs,
    const float* __restrict__ PL, const float* __restrict__ LN,
    const float* __restrict__ aabb, float* __restrict__ out, int N)
{
    int n = blockIdx.x * 256 + threadIdx.x;
    if (n >= N) return;

    float px = xyz[3 * n + 0], py = xyz[3 * n + 1], pz = xyz[3 * n + 2];
    float xn[3];
    xn[0] = (px - aabb[0]) * (2.0f / (aabb[3] - aabb[0])) - 1.0f;
    xn[1] = (py - aabb[1]) * (2.0f / (aabb[4] - aabb[1])) - 1.0f;
    xn[2] = (pz - aabb[2]) * (2.0f / (aabb[5] - aabb[2])) - 1.0f;

    float bw[6] = {0.f, 0.f, 0.f, 0.f, 0.f, 0.f};

    #pragma unroll
    for (int p = 0; p < 3; ++p) {
        constexpr int M0[3] = {0, 0, 1};
        constexpr int M1[3] = {1, 2, 2};
        constexpr int MV[3] = {2, 1, 0};
        int x0, x1, y0, y1, z0, z1;
        float wx, wy, wz;
        axis_setup(xn[M0[p]], x0, x1, wx);
        axis_setup(xn[M1[p]], y0, y1, wy);
        axis_setup(xn[MV[p]], z0, z1, wz);
        float w00 = (1.f - wx) * (1.f - wy);
        float w01 = wx * (1.f - wy);
        float w10 = (1.f - wx) * wy;
        float w11 = wx * wy;
        float uz = 1.f - wz;
        #pragma unroll
        for (int s = 0; s < 6; ++s) {
            float acc = bw[s];
            for (int c = 0; c < 16; ++c) {
                int sc = s * 16 + c;
                const float* pb = PL + (size_t)(p * SC + sc) * (GRES * GRES);
                float f00 = pb[y0 * GRES + x0];
                float f01 = pb[y0 * GRES + x1];
                float f10 = pb[y1 * GRES + x0];
                float f11 = pb[y1 * GRES + x1];
                const float* lb = LN + (size_t)(p * SC + sc) * GRES;
                float lv = fmaf(lb[z0], uz, lb[z1] * wz);
                float pv = fmaf(f00, w00, fmaf(f01, w01, fmaf(f10, w10, f11 * w11)));
                acc = fmaf(pv, lv, acc);
            }
            bw[s] = acc;
        }
    }

    float wxr = bw[0], wyr = bw[1], wzr = bw[2];
    float dotw = wxr * wxr + wyr * wyr + wzr * wzr;
    float theta = sqrtf(fmaxf(dotw, 1e-6f));
    float it = 1.0f / theta;
    float ux = wxr * it, uy = wyr * it, un = wzr * it;
    float vx = bw[3] * it, vy = bw[4] * it, vz = bw[5] * it;
    float st, ct;
    sincosf(theta, &st, &ct);
    float q   = ux * ux + uy * uy + un * un;
    float omc = 1.0f - ct;
    float ra = 1.0f - omc * q;
    float R00 = ra + omc * ux * ux;
    float R01 = omc * ux * uy - st * un;
    float R02 = omc * ux * un + st * uy;
    float R10 = omc * uy * ux + st * un;
    float R11 = ra + omc * uy * uy;
    float R12 = omc * uy * un - st * ux;
    float R20 = omc * un * ux - st * uy;
    float R21 = omc * un * uy + st * ux;
    float R22 = ra + omc * un * un;
    float tms = theta - st;
    float pa  = theta - tms * q;
    float P00 = pa + tms * ux * ux;
    float P01 = tms * ux * uy - omc * un;
    float P02 = tms * ux * un + omc * uy;
    float P10 = tms * uy * ux + omc * un;
    float P11 = pa + tms * uy * uy;
    float P12 = tms * uy * un - omc * ux;
    float P20 = tms * un * ux - omc * uy;
    float P21 = tms * un * uy + omc * ux;
    float P22 = pa + tms * un * un;

    float tx = P00 * vx + P01 * vy + P02 * vz;
    float ty = P10 * vx + P11 * vy + P12 * vz;
    float tz = P20 * vx + P21 * vy + P22 * vz;

    float ox = R00 * px + R01 * py + R02 * pz + tx;
    float oy = R10 * px + R11 * py + R12 * pz + ty;
    float oz = R20 * px + R21 * py + R22 * pz + tz;

    float dx = vdirs[3 * n + 0], dy = vdirs[3 * n + 1], dz = vdirs[3 * n + 2];
    float wvx = R00 * dx + R01 * dy + R02 * dz;
    float wvy = R10 * dx + R11 * dy + R12 * dz;
    float wvz = R20 * dx + R21 * dy + R22 * dz;

    out[3 * n + 0] = ox;
    out[3 * n + 1] = oy;
    out[3 * n + 2] = oz;
    size_t off = (size_t)3 * N;
    out[off + 3 * n + 0] = wvx;
    out[off + 3 * n + 1] = wvy;
    out[off + 3 * n + 2] = wvz;
}

extern "C" void kernel_launch(void* const* d_in, const int* in_sizes, int n_in,
                              void* d_out, int out_size, void* d_ws, size_t ws_size,
                              hipStream_t stream)
{
    const float* xyz    = (const float*)d_in[0];
    const float* vd     = (const float*)d_in[1];
    // d_in[2] = transforms (unused), d_in[3] = ray_valid (unused)
    const float* planes = (const float*)d_in[4];
    const float* lines  = (const float*)d_in[5];
    const float* aabb   = (const float*)d_in[6];
    float* out = (float*)d_out;

    int N = in_sizes[0] / 3;   // 524288

    size_t needP = (size_t)3 * GRES * GRES * SC * sizeof(float);  // 18.87 MB
    size_t needL = (size_t)3 * GRES * SC * sizeof(float);         // 147 KB

    if (ws_size >= needP + needL) {
        float* TP = (float*)d_ws;
        float* TL = TP + (size_t)3 * GRES * GRES * SC;
        tp_planes<<<3 * GRES, 256, 0, stream>>>(planes, TP);
        tp_lines<<<(3 * GRES * SC + 255) / 256, 256, 0, stream>>>(lines, TL);
        int threads = N * 4;
        bwcast_fast4<<<(threads + 255) / 256, 256, 0, stream>>>(xyz, vd, TP, TL, aabb, out, N);
    } else {
        bwcast_direct<<<(N + 255) / 256, 256, 0, stream>>>(xyz, vd, planes, lines, aabb, out, N);
    }
}

// Round 3
// 231.058 us; speedup vs baseline: 3.5757x; 1.7927x over previous
//
#include <hip/hip_runtime.h>
#include <hip/hip_fp16.h>
#include <cstdint>
#include <cstddef>

#define GRES 128   // grid resolution (H = W = L)
#define SC   96    // S*C = 6*16 channels

// ---------------------------------------------------------------------------
// Transpose + quantize planes [p][sc][y][x] (f32) -> [p][y][x][sc] (fp16).
// 96 halves = 192 B contiguous per texel, 16B-aligned.
// ---------------------------------------------------------------------------
__global__ __launch_bounds__(256) void tp_planes(const float* __restrict__ in,
                                                 __half* __restrict__ out)
{
    __shared__ float tile[SC][GRES + 1];
    int py = blockIdx.x;            // p*128 + y
    int p  = py >> 7;
    int y  = py & 127;
    const float* src = in + (size_t)p * SC * GRES * GRES + (size_t)y * GRES;
    for (int i = threadIdx.x; i < SC * GRES; i += 256) {
        int sc = i >> 7;            // channel
        int x  = i & 127;
        tile[sc][x] = src[(size_t)sc * (GRES * GRES) + x];   // coalesced rows
    }
    __syncthreads();
    __half* dst = out + (size_t)py * GRES * SC;
    for (int i = threadIdx.x; i < SC * GRES; i += 256) {
        int x  = i / SC;
        int sc = i - x * SC;
        dst[i] = __float2half(tile[sc][x]);   // coalesced, conflict-free LDS
    }
}

// Transpose + quantize lines [p][sc][z] -> [p][z][sc] fp16. Tiny.
__global__ __launch_bounds__(256) void tp_lines(const float* __restrict__ in,
                                                __half* __restrict__ out)
{
    int i = blockIdx.x * 256 + threadIdx.x;
    if (i >= 3 * GRES * SC) return;
    int p  = i / (GRES * SC);
    int r  = i - p * (GRES * SC);
    int z  = r / SC;
    int sc = r - z * SC;
    out[i] = __float2half(in[((size_t)p * SC + sc) * GRES + z]);
}

__device__ __forceinline__ void axis_setup(float xnv, int& i0, int& i1, float& w)
{
    float f = (xnv + 1.0f) * 0.5f * (float)(GRES - 1);
    f = fminf(fmaxf(f, 0.0f), (float)(GRES - 1));
    float ff = floorf(f);
    i0 = (int)ff;
    i1 = min(i0 + 1, GRES - 1);
    w  = f - ff;
}

// Load 8 contiguous halves (16 B) and widen to f32.
__device__ __forceinline__ void ld8(const __half* p, float f[8])
{
    uint4 q = *reinterpret_cast<const uint4*>(p);
    const __half2* h = reinterpret_cast<const __half2*>(&q);
    float2 a0 = __half22float2(h[0]);
    float2 a1 = __half22float2(h[1]);
    float2 a2 = __half22float2(h[2]);
    float2 a3 = __half22float2(h[3]);
    f[0] = a0.x; f[1] = a0.y; f[2] = a1.x; f[3] = a1.y;
    f[4] = a2.x; f[5] = a2.y; f[6] = a3.x; f[7] = a3.y;
}

// ---------------------------------------------------------------------------
// Main kernel: FOUR lanes per point, fp16 feature buffers.
// Lane l, iter k reads channels [32k + 8l, +8): all within s = 2k + (l>>1).
// Reduce: xor1 (channel halves of same s), xor2 (swap even/odd s-groups).
// ---------------------------------------------------------------------------
__global__ __launch_bounds__(256) void bwcast_h4(
    const float* __restrict__ xyz, const float* __restrict__ vdirs,
    const __half* __restrict__ TP, const __half* __restrict__ TL,
    const float* __restrict__ aabb, float* __restrict__ out, int N)
{
    int t = blockIdx.x * 256 + threadIdx.x;
    int n = t >> 2;          // point index
    int l = t & 3;           // sub-lane within point
    if (n >= N) return;

    float px = xyz[3 * n + 0], py = xyz[3 * n + 1], pz = xyz[3 * n + 2];
    float xn[3];
    xn[0] = (px - aabb[0]) * (2.0f / (aabb[3] - aabb[0])) - 1.0f;
    xn[1] = (py - aabb[1]) * (2.0f / (aabb[4] - aabb[1])) - 1.0f;
    xn[2] = (pz - aabb[2]) * (2.0f / (aabb[5] - aabb[2])) - 1.0f;

    float part[3] = {0.f, 0.f, 0.f};
    const int loff = l * 8;  // half-offset of this lane's 8-ch chunk within 32

    #pragma unroll
    for (int p = 0; p < 3; ++p) {
        constexpr int M0[3] = {0, 0, 1};
        constexpr int M1[3] = {1, 2, 2};
        constexpr int MV[3] = {2, 1, 0};
        int x0, x1, y0, y1, z0, z1;
        float wx, wy, wz;
        axis_setup(xn[M0[p]], x0, x1, wx);
        axis_setup(xn[M1[p]], y0, y1, wy);
        axis_setup(xn[MV[p]], z0, z1, wz);

        const __half* c00 = TP + (size_t)((p * GRES + y0) * GRES + x0) * SC + loff;
        const __half* c01 = TP + (size_t)((p * GRES + y0) * GRES + x1) * SC + loff;
        const __half* c10 = TP + (size_t)((p * GRES + y1) * GRES + x0) * SC + loff;
        const __half* c11 = TP + (size_t)((p * GRES + y1) * GRES + x1) * SC + loff;
        const __half* l0  = TL + (size_t)(p * GRES + z0) * SC + loff;
        const __half* l1  = TL + (size_t)(p * GRES + z1) * SC + loff;

        float w00 = (1.f - wx) * (1.f - wy);
        float w01 = wx * (1.f - wy);
        float w10 = (1.f - wx) * wy;
        float w11 = wx * wy;
        float uz = 1.f - wz;

        #pragma unroll
        for (int k = 0; k < 3; ++k) {
            const int off = k * 32;
            float f00[8], f01[8], f10[8], f11[8], g0[8], g1[8];
            ld8(c00 + off, f00);
            ld8(c01 + off, f01);
            ld8(c10 + off, f10);
            ld8(c11 + off, f11);
            ld8(l0 + off, g0);
            ld8(l1 + off, g1);
            float acc = part[k];
            #pragma unroll
            for (int j = 0; j < 8; ++j) {
                float pv = fmaf(f00[j], w00, fmaf(f01[j], w01, fmaf(f10[j], w10, f11[j] * w11)));
                float lv = fmaf(g0[j], uz, g1[j] * wz);
                acc = fmaf(pv, lv, acc);
            }
            part[k] = acc;
        }
    }

    // Cross-lane reduce within the 4-lane group.
    float bw[6];
    const int half_id = l >> 1;        // 0: even s-groups, 1: odd
    #pragma unroll
    for (int k = 0; k < 3; ++k) {
        float v = part[k];
        v += __shfl_xor(v, 1);         // sum the two 8-ch halves of same s
        float o = __shfl_xor(v, 2);    // fetch the other parity's sum
        bw[2 * k + half_id]       = v;
        bw[2 * k + (1 - half_id)] = o;
    }

    // ---- Rodrigues / screw transform (all 4 lanes redundantly) ----
    float wxr = bw[0], wyr = bw[1], wzr = bw[2];
    float dotw = wxr * wxr + wyr * wyr + wzr * wzr;
    float theta = sqrtf(fmaxf(dotw, 1e-6f));
    float it = 1.0f / theta;
    float ux = wxr * it, uy = wyr * it, un = wzr * it;
    float vx = bw[3] * it, vy = bw[4] * it, vz = bw[5] * it;
    float st, ct;
    sincosf(theta, &st, &ct);
    float q   = ux * ux + uy * uy + un * un;   // == 1 unless theta clipped
    float omc = 1.0f - ct;
    float ra = 1.0f - omc * q;                 // skew(u)^2 = uu^T - q I
    float R00 = ra + omc * ux * ux;
    float R01 = omc * ux * uy - st * un;
    float R02 = omc * ux * un + st * uy;
    float R10 = omc * uy * ux + st * un;
    float R11 = ra + omc * uy * uy;
    float R12 = omc * uy * un - st * ux;
    float R20 = omc * un * ux - st * uy;
    float R21 = omc * un * uy + st * ux;
    float R22 = ra + omc * un * un;
    float tms = theta - st;
    float pa  = theta - tms * q;
    float P00 = pa + tms * ux * ux;
    float P01 = tms * ux * uy - omc * un;
    float P02 = tms * ux * un + omc * uy;
    float P10 = tms * uy * ux + omc * un;
    float P11 = pa + tms * uy * uy;
    float P12 = tms * uy * un - omc * ux;
    float P20 = tms * un * ux - omc * uy;
    float P21 = tms * un * uy + omc * ux;
    float P22 = pa + tms * un * un;

    float tx = P00 * vx + P01 * vy + P02 * vz;
    float ty = P10 * vx + P11 * vy + P12 * vz;
    float tz = P20 * vx + P21 * vy + P22 * vz;

    float ox = R00 * px + R01 * py + R02 * pz + tx;
    float oy = R10 * px + R11 * py + R12 * pz + ty;
    float oz = R20 * px + R21 * py + R22 * pz + tz;

    float dx = vdirs[3 * n + 0], dy = vdirs[3 * n + 1], dz = vdirs[3 * n + 2];
    float wvx = R00 * dx + R01 * dy + R02 * dz;
    float wvy = R10 * dx + R11 * dy + R12 * dz;
    float wvz = R20 * dx + R21 * dy + R22 * dz;

    // Lane l < 3 writes component l of both outputs.
    if (l < 3) {
        float o  = (l == 0) ? ox : (l == 1) ? oy : oz;
        float wv = (l == 0) ? wvx : (l == 1) ? wvy : wvz;
        out[3 * n + l] = o;
        out[(size_t)3 * N + 3 * n + l] = wv;
    }
}

// ---------------------------------------------------------------------------
// Fallback: original layouts, f32 (only if d_ws too small).
// ---------------------------------------------------------------------------
__global__ __launch_bounds__(256) void bwcast_direct(
    const float* __restrict__ xyz, const float* __restrict__ vdirs,
    const float* __restrict__ PL, const float* __restrict__ LN,
    const float* __restrict__ aabb, float* __restrict__ out, int N)
{
    int n = blockIdx.x * 256 + threadIdx.x;
    if (n >= N) return;

    float px = xyz[3 * n + 0], py = xyz[3 * n + 1], pz = xyz[3 * n + 2];
    float xn[3];
    xn[0] = (px - aabb[0]) * (2.0f / (aabb[3] - aabb[0])) - 1.0f;
    xn[1] = (py - aabb[1]) * (2.0f / (aabb[4] - aabb[1])) - 1.0f;
    xn[2] = (pz - aabb[2]) * (2.0f / (aabb[5] - aabb[2])) - 1.0f;

    float bw[6] = {0.f, 0.f, 0.f, 0.f, 0.f, 0.f};

    #pragma unroll
    for (int p = 0; p < 3; ++p) {
        constexpr int M0[3] = {0, 0, 1};
        constexpr int M1[3] = {1, 2, 2};
        constexpr int MV[3] = {2, 1, 0};
        int x0, x1, y0, y1, z0, z1;
        float wx, wy, wz;
        axis_setup(xn[M0[p]], x0, x1, wx);
        axis_setup(xn[M1[p]], y0, y1, wy);
        axis_setup(xn[MV[p]], z0, z1, wz);
        float w00 = (1.f - wx) * (1.f - wy);
        float w01 = wx * (1.f - wy);
        float w10 = (1.f - wx) * wy;
        float w11 = wx * wy;
        float uz = 1.f - wz;
        #pragma unroll
        for (int s = 0; s < 6; ++s) {
            float acc = bw[s];
            for (int c = 0; c < 16; ++c) {
                int sc = s * 16 + c;
                const float* pb = PL + (size_t)(p * SC + sc) * (GRES * GRES);
                float f00 = pb[y0 * GRES + x0];
                float f01 = pb[y0 * GRES + x1];
                float f10 = pb[y1 * GRES + x0];
                float f11 = pb[y1 * GRES + x1];
                const float* lb = LN + (size_t)(p * SC + sc) * GRES;
                float lv = fmaf(lb[z0], uz, lb[z1] * wz);
                float pv = fmaf(f00, w00, fmaf(f01, w01, fmaf(f10, w10, f11 * w11)));
                acc = fmaf(pv, lv, acc);
            }
            bw[s] = acc;
        }
    }

    float wxr = bw[0], wyr = bw[1], wzr = bw[2];
    float dotw = wxr * wxr + wyr * wyr + wzr * wzr;
    float theta = sqrtf(fmaxf(dotw, 1e-6f));
    float it = 1.0f / theta;
    float ux = wxr * it, uy = wyr * it, un = wzr * it;
    float vx = bw[3] * it, vy = bw[4] * it, vz = bw[5] * it;
    float st, ct;
    sincosf(theta, &st, &ct);
    float q   = ux * ux + uy * uy + un * un;
    float omc = 1.0f - ct;
    float ra = 1.0f - omc * q;
    float R00 = ra + omc * ux * ux;
    float R01 = omc * ux * uy - st * un;
    float R02 = omc * ux * un + st * uy;
    float R10 = omc * uy * ux + st * un;
    float R11 = ra + omc * uy * uy;
    float R12 = omc * uy * un - st * ux;
    float R20 = omc * un * ux - st * uy;
    float R21 = omc * un * uy + st * ux;
    float R22 = ra + omc * un * un;
    float tms = theta - st;
    float pa  = theta - tms * q;
    float P00 = pa + tms * ux * ux;
    float P01 = tms * ux * uy - omc * un;
    float P02 = tms * ux * un + omc * uy;
    float P10 = tms * uy * ux + omc * un;
    float P11 = pa + tms * uy * uy;
    float P12 = tms * uy * un - omc * ux;
    float P20 = tms * un * ux - omc * uy;
    float P21 = tms * un * uy + omc * ux;
    float P22 = pa + tms * un * un;

    float tx = P00 * vx + P01 * vy + P02 * vz;
    float ty = P10 * vx + P11 * vy + P12 * vz;
    float tz = P20 * vx + P21 * vy + P22 * vz;

    float ox = R00 * px + R01 * py + R02 * pz + tx;
    float oy = R10 * px + R11 * py + R12 * pz + ty;
    float oz = R20 * px + R21 * py + R22 * pz + tz;

    float dx = vdirs[3 * n + 0], dy = vdirs[3 * n + 1], dz = vdirs[3 * n + 2];
    float wvx = R00 * dx + R01 * dy + R02 * dz;
    float wvy = R10 * dx + R11 * dy + R12 * dz;
    float wvz = R20 * dx + R21 * dy + R22 * dz;

    out[3 * n + 0] = ox;
    out[3 * n + 1] = oy;
    out[3 * n + 2] = oz;
    size_t off = (size_t)3 * N;
    out[off + 3 * n + 0] = wvx;
    out[off + 3 * n + 1] = wvy;
    out[off + 3 * n + 2] = wvz;
}

extern "C" void kernel_launch(void* const* d_in, const int* in_sizes, int n_in,
                              void* d_out, int out_size, void* d_ws, size_t ws_size,
                              hipStream_t stream)
{
    const float* xyz    = (const float*)d_in[0];
    const float* vd     = (const float*)d_in[1];
    // d_in[2] = transforms (unused), d_in[3] = ray_valid (unused)
    const float* planes = (const float*)d_in[4];
    const float* lines  = (const float*)d_in[5];
    const float* aabb   = (const float*)d_in[6];
    float* out = (float*)d_out;

    int N = in_sizes[0] / 3;   // 524288

    size_t needP = (size_t)3 * GRES * GRES * SC * sizeof(__half);  // 9.44 MB
    size_t needL = (size_t)3 * GRES * SC * sizeof(__half);         // 73.7 KB

    if (ws_size >= needP + needL) {
        __half* TP = (__half*)d_ws;
        __half* TL = TP + (size_t)3 * GRES * GRES * SC;
        tp_planes<<<3 * GRES, 256, 0, stream>>>(planes, TP);
        tp_lines<<<(3 * GRES * SC + 255) / 256, 256, 0, stream>>>(lines, TL);
        int threads = N * 4;
        bwcast_h4<<<(threads + 255) / 256, 256, 0, stream>>>(xyz, vd, TP, TL, aabb, out, N);
    } else {
        bwcast_direct<<<(N + 255) / 256, 256, 0, stream>>>(xyz, vd, planes, lines, aabb, out, N);
    }
}

// Round 4
// 198.267 us; speedup vs baseline: 4.1671x; 1.1654x over previous
//
#include <hip/hip_runtime.h>
#include <hip/hip_fp16.h>
#include <cstdint>
#include <cstddef>

#define GRES 128   // grid resolution (H = W = L)
#define SC   96    // S*C = 6*16 channels

typedef float v2f __attribute__((ext_vector_type(2)));

// ---------------------------------------------------------------------------
// Transpose + quantize planes [p][sc][y][x] f32 -> [p][y][x][96 x fp8 bytes].
// Block = (p, y, 32-channel tile). Packed 4 channels per uint32 store.
// ---------------------------------------------------------------------------
__global__ __launch_bounds__(256) void tp_planes_fp8(const float* __restrict__ in,
                                                     uint32_t* __restrict__ out)
{
    __shared__ float tile[32][GRES + 1];
    int b  = blockIdx.x;            // ((p*128 + y)*3 + ct)
    int ct = b % 3;
    int py = b / 3;
    int p  = py >> 7;
    int y  = py & 127;
    const float* src = in + ((size_t)(p * SC + ct * 32) * GRES + y) * GRES;
    for (int i = threadIdx.x; i < 32 * GRES; i += 256) {
        int sc = i >> 7;
        int x  = i & 127;
        tile[sc][x] = src[(size_t)sc * (GRES * GRES) + x];   // coalesced rows
    }
    __syncthreads();
    uint32_t* dst = out + (size_t)py * GRES * 24 + ct * 8;   // 24 uints per texel
    for (int u = threadIdx.x; u < GRES * 8; u += 256) {
        int x  = u >> 3;
        int c4 = u & 7;
        int c0 = c4 * 4;
        uint32_t acc = 0;
        acc = __builtin_amdgcn_cvt_pk_fp8_f32(tile[c0 + 0][x], tile[c0 + 1][x], acc, false);
        acc = __builtin_amdgcn_cvt_pk_fp8_f32(tile[c0 + 2][x], tile[c0 + 3][x], acc, true);
        dst[(size_t)x * 24 + c4] = acc;
    }
}

// Transpose + quantize lines [p][sc][z] -> [p][z][sc] fp16. Tiny.
__global__ __launch_bounds__(256) void tp_lines(const float* __restrict__ in,
                                                __half* __restrict__ out)
{
    int i = blockIdx.x * 256 + threadIdx.x;
    if (i >= 3 * GRES * SC) return;
    int p  = i / (GRES * SC);
    int r  = i - p * (GRES * SC);
    int z  = r / SC;
    int sc = r - z * SC;
    out[i] = __float2half(in[((size_t)p * SC + sc) * GRES + z]);
}

__device__ __forceinline__ void axis_setup(float xnv, int& i0, int& i1, float& w)
{
    float f = (xnv + 1.0f) * 0.5f * (float)(GRES - 1);
    f = fminf(fmaxf(f, 0.0f), (float)(GRES - 1));
    float ff = floorf(f);
    i0 = (int)ff;
    i1 = min(i0 + 1, GRES - 1);
    w  = f - ff;
}

__device__ __forceinline__ uint32_t u4c(const uint4& q, int c)
{
    return c == 0 ? q.x : c == 1 ? q.y : c == 2 ? q.z : q.w;
}

// ---------------------------------------------------------------------------
// Main kernel: TWO lanes per point, fp8 planes / fp16 lines.
// Lane l, iter k owns the full 16-channel block s = 2k + l.
// Per k, ALL 24 loads (3 modes x (4 plane corners + 2 line taps x 2)) issue
// before any consumption -> ~384 B in flight per thread.
// ---------------------------------------------------------------------------
__global__ __launch_bounds__(256, 3) void bwcast_q2(
    const float* __restrict__ xyz, const float* __restrict__ vdirs,
    const uint8_t* __restrict__ TP, const __half* __restrict__ TL,
    const float* __restrict__ aabb, float* __restrict__ out, int N)
{
    int t = blockIdx.x * 256 + threadIdx.x;
    int n = t >> 1;          // point index
    int l = t & 1;           // sub-lane within point
    if (n >= N) return;

    float px = xyz[3 * n + 0], py = xyz[3 * n + 1], pz = xyz[3 * n + 2];
    float xn[3];
    xn[0] = (px - aabb[0]) * (2.0f / (aabb[3] - aabb[0])) - 1.0f;
    xn[1] = (py - aabb[1]) * (2.0f / (aabb[4] - aabb[1])) - 1.0f;
    xn[2] = (pz - aabb[2]) * (2.0f / (aabb[5] - aabb[2])) - 1.0f;

    uint32_t pofs[3][4];     // byte offsets into TP
    uint32_t lofs[3][2];     // element (half) offsets into TL
    float W[3][4], UZ[3], WZ[3];

    #pragma unroll
    for (int p = 0; p < 3; ++p) {
        constexpr int M0[3] = {0, 0, 1};
        constexpr int M1[3] = {1, 2, 2};
        constexpr int MV[3] = {2, 1, 0};
        int x0, x1, y0, y1, z0, z1;
        float wx, wy, wz;
        axis_setup(xn[M0[p]], x0, x1, wx);
        axis_setup(xn[M1[p]], y0, y1, wy);
        axis_setup(xn[MV[p]], z0, z1, wz);
        uint32_t base = (uint32_t)l * 16u;
        pofs[p][0] = (uint32_t)((p * GRES + y0) * GRES + x0) * 96u + base;
        pofs[p][1] = (uint32_t)((p * GRES + y0) * GRES + x1) * 96u + base;
        pofs[p][2] = (uint32_t)((p * GRES + y1) * GRES + x0) * 96u + base;
        pofs[p][3] = (uint32_t)((p * GRES + y1) * GRES + x1) * 96u + base;
        lofs[p][0] = (uint32_t)((p * GRES + z0) * SC) + (uint32_t)l * 16u;
        lofs[p][1] = (uint32_t)((p * GRES + z1) * SC) + (uint32_t)l * 16u;
        W[p][0] = (1.f - wx) * (1.f - wy);
        W[p][1] = wx * (1.f - wy);
        W[p][2] = (1.f - wx) * wy;
        W[p][3] = wx * wy;
        UZ[p] = 1.f - wz;
        WZ[p] = wz;
    }

    float part[3] = {0.f, 0.f, 0.f};

    #pragma unroll
    for (int k = 0; k < 3; ++k) {
        // ---- issue all loads for this k (channels 32k+16l .. +16) ----
        uint4 pq[3][4];
        uint4 lq[3][2][2];
        #pragma unroll
        for (int p = 0; p < 3; ++p) {
            #pragma unroll
            for (int c = 0; c < 4; ++c)
                pq[p][c] = *(const uint4*)(TP + pofs[p][c] + k * 32);
        }
        #pragma unroll
        for (int p = 0; p < 3; ++p) {
            #pragma unroll
            for (int d = 0; d < 2; ++d) {
                const __half* lp = TL + lofs[p][d] + k * 32;
                lq[p][d][0] = *(const uint4*)(lp);
                lq[p][d][1] = *(const uint4*)(lp + 8);
            }
        }
        // ---- consume ----
        float acc = part[k];
        #pragma unroll
        for (int p = 0; p < 3; ++p) {
            float w0 = W[p][0], w1 = W[p][1], w2 = W[p][2], w3 = W[p][3];
            float uz = UZ[p], wz = WZ[p];
            #pragma unroll
            for (int cc = 0; cc < 4; ++cc) {       // channels 4cc .. 4cc+3
                uint32_t q0 = u4c(pq[p][0], cc);
                uint32_t q1 = u4c(pq[p][1], cc);
                uint32_t q2 = u4c(pq[p][2], cc);
                uint32_t q3 = u4c(pq[p][3], cc);
                uint32_t l0a = u4c(lq[p][0][cc >> 1], (cc & 1) ? 2 : 0);
                uint32_t l0b = u4c(lq[p][0][cc >> 1], (cc & 1) ? 3 : 1);
                uint32_t l1a = u4c(lq[p][1][cc >> 1], (cc & 1) ? 2 : 0);
                uint32_t l1b = u4c(lq[p][1][cc >> 1], (cc & 1) ? 3 : 1);
                v2f fa0 = __builtin_amdgcn_cvt_pk_f32_fp8(q0, false);
                v2f fa1 = __builtin_amdgcn_cvt_pk_f32_fp8(q1, false);
                v2f fa2 = __builtin_amdgcn_cvt_pk_f32_fp8(q2, false);
                v2f fa3 = __builtin_amdgcn_cvt_pk_f32_fp8(q3, false);
                v2f fb0 = __builtin_amdgcn_cvt_pk_f32_fp8(q0, true);
                v2f fb1 = __builtin_amdgcn_cvt_pk_f32_fp8(q1, true);
                v2f fb2 = __builtin_amdgcn_cvt_pk_f32_fp8(q2, true);
                v2f fb3 = __builtin_amdgcn_cvt_pk_f32_fp8(q3, true);
                float2 g0lo = __half22float2(*reinterpret_cast<const __half2*>(&l0a));
                float2 g0hi = __half22float2(*reinterpret_cast<const __half2*>(&l0b));
                float2 g1lo = __half22float2(*reinterpret_cast<const __half2*>(&l1a));
                float2 g1hi = __half22float2(*reinterpret_cast<const __half2*>(&l1b));
                {
                    float pv = fmaf(fa0[0], w0, fmaf(fa1[0], w1, fmaf(fa2[0], w2, fa3[0] * w3)));
                    float lv = fmaf(g0lo.x, uz, g1lo.x * wz);
                    acc = fmaf(pv, lv, acc);
                }
                {
                    float pv = fmaf(fa0[1], w0, fmaf(fa1[1], w1, fmaf(fa2[1], w2, fa3[1] * w3)));
                    float lv = fmaf(g0lo.y, uz, g1lo.y * wz);
                    acc = fmaf(pv, lv, acc);
                }
                {
                    float pv = fmaf(fb0[0], w0, fmaf(fb1[0], w1, fmaf(fb2[0], w2, fb3[0] * w3)));
                    float lv = fmaf(g0hi.x, uz, g1hi.x * wz);
                    acc = fmaf(pv, lv, acc);
                }
                {
                    float pv = fmaf(fb0[1], w0, fmaf(fb1[1], w1, fmaf(fb2[1], w2, fb3[1] * w3)));
                    float lv = fmaf(g0hi.y, uz, g1hi.y * wz);
                    acc = fmaf(pv, lv, acc);
                }
            }
        }
        part[k] = acc;
    }

    // Cross-lane exchange: lane l holds s = 2k + l fully computed.
    float bw[6];
    #pragma unroll
    for (int k = 0; k < 3; ++k) {
        float e = part[k];
        float o = __shfl_xor(e, 1);
        bw[2 * k + 0] = (l == 0) ? e : o;
        bw[2 * k + 1] = (l == 0) ? o : e;
    }

    // ---- Rodrigues / screw transform (both lanes redundantly) ----
    float wxr = bw[0], wyr = bw[1], wzr = bw[2];
    float dotw = wxr * wxr + wyr * wyr + wzr * wzr;
    float theta = sqrtf(fmaxf(dotw, 1e-6f));
    float it = 1.0f / theta;
    float ux = wxr * it, uy = wyr * it, un = wzr * it;
    float vx = bw[3] * it, vy = bw[4] * it, vz = bw[5] * it;
    float st, ct;
    sincosf(theta, &st, &ct);
    float q   = ux * ux + uy * uy + un * un;   // == 1 unless theta clipped
    float omc = 1.0f - ct;
    float ra = 1.0f - omc * q;                 // skew(u)^2 = uu^T - q I
    float R00 = ra + omc * ux * ux;
    float R01 = omc * ux * uy - st * un;
    float R02 = omc * ux * un + st * uy;
    float R10 = omc * uy * ux + st * un;
    float R11 = ra + omc * uy * uy;
    float R12 = omc * uy * un - st * ux;
    float R20 = omc * un * ux - st * uy;
    float R21 = omc * un * uy + st * ux;
    float R22 = ra + omc * un * un;
    float tms = theta - st;
    float pa  = theta - tms * q;
    float P00 = pa + tms * ux * ux;
    float P01 = tms * ux * uy - omc * un;
    float P02 = tms * ux * un + omc * uy;
    float P10 = tms * uy * ux + omc * un;
    float P11 = pa + tms * uy * uy;
    float P12 = tms * uy * un - omc * ux;
    float P20 = tms * un * ux - omc * uy;
    float P21 = tms * un * uy + omc * ux;
    float P22 = pa + tms * un * un;

    if (l == 0) {
        float tx = P00 * vx + P01 * vy + P02 * vz;
        float ty = P10 * vx + P11 * vy + P12 * vz;
        float tz = P20 * vx + P21 * vy + P22 * vz;
        out[3 * n + 0] = R00 * px + R01 * py + R02 * pz + tx;
        out[3 * n + 1] = R10 * px + R11 * py + R12 * pz + ty;
        out[3 * n + 2] = R20 * px + R21 * py + R22 * pz + tz;
    } else {
        float dx = vdirs[3 * n + 0], dy = vdirs[3 * n + 1], dz = vdirs[3 * n + 2];
        size_t off = (size_t)3 * N;
        out[off + 3 * n + 0] = R00 * dx + R01 * dy + R02 * dz;
        out[off + 3 * n + 1] = R10 * dx + R11 * dy + R12 * dz;
        out[off + 3 * n + 2] = R20 * dx + R21 * dy + R22 * dz;
    }
}

// ---------------------------------------------------------------------------
// Fallback: original layouts, f32 (only if d_ws too small).
// ---------------------------------------------------------------------------
__global__ __launch_bounds__(256) void bwcast_direct(
    const float* __restrict__ xyz, const float* __restrict__ vdirs,
    const float* __restrict__ PL, const float* __restrict__ LN,
    const float* __restrict__ aabb, float* __restrict__ out, int N)
{
    int n = blockIdx.x * 256 + threadIdx.x;
    if (n >= N) return;

    float px = xyz[3 * n + 0], py = xyz[3 * n + 1], pz = xyz[3 * n + 2];
    float xn[3];
    xn[0] = (px - aabb[0]) * (2.0f / (aabb[3] - aabb[0])) - 1.0f;
    xn[1] = (py - aabb[1]) * (2.0f / (aabb[4] - aabb[1])) - 1.0f;
    xn[2] = (pz - aabb[2]) * (2.0f / (aabb[5] - aabb[2])) - 1.0f;

    float bw[6] = {0.f, 0.f, 0.f, 0.f, 0.f, 0.f};

    #pragma unroll
    for (int p = 0; p < 3; ++p) {
        constexpr int M0[3] = {0, 0, 1};
        constexpr int M1[3] = {1, 2, 2};
        constexpr int MV[3] = {2, 1, 0};
        int x0, x1, y0, y1, z0, z1;
        float wx, wy, wz;
        axis_setup(xn[M0[p]], x0, x1, wx);
        axis_setup(xn[M1[p]], y0, y1, wy);
        axis_setup(xn[MV[p]], z0, z1, wz);
        float w00 = (1.f - wx) * (1.f - wy);
        float w01 = wx * (1.f - wy);
        float w10 = (1.f - wx) * wy;
        float w11 = wx * wy;
        float uz = 1.f - wz;
        #pragma unroll
        for (int s = 0; s < 6; ++s) {
            float acc = bw[s];
            for (int c = 0; c < 16; ++c) {
                int sc = s * 16 + c;
                const float* pb = PL + (size_t)(p * SC + sc) * (GRES * GRES);
                float f00 = pb[y0 * GRES + x0];
                float f01 = pb[y0 * GRES + x1];
                float f10 = pb[y1 * GRES + x0];
                float f11 = pb[y1 * GRES + x1];
                const float* lb = LN + (size_t)(p * SC + sc) * GRES;
                float lv = fmaf(lb[z0], uz, lb[z1] * wz);
                float pv = fmaf(f00, w00, fmaf(f01, w01, fmaf(f10, w10, f11 * w11)));
                acc = fmaf(pv, lv, acc);
            }
            bw[s] = acc;
        }
    }

    float wxr = bw[0], wyr = bw[1], wzr = bw[2];
    float dotw = wxr * wxr + wyr * wyr + wzr * wzr;
    float theta = sqrtf(fmaxf(dotw, 1e-6f));
    float it = 1.0f / theta;
    float ux = wxr * it, uy = wyr * it, un = wzr * it;
    float vx = bw[3] * it, vy = bw[4] * it, vz = bw[5] * it;
    float st, ct;
    sincosf(theta, &st, &ct);
    float q   = ux * ux + uy * uy + un * un;
    float omc = 1.0f - ct;
    float ra = 1.0f - omc * q;
    float R00 = ra + omc * ux * ux;
    float R01 = omc * ux * uy - st * un;
    float R02 = omc * ux * un + st * uy;
    float R10 = omc * uy * ux + st * un;
    float R11 = ra + omc * uy * uy;
    float R12 = omc * uy * un - st * ux;
    float R20 = omc * un * ux - st * uy;
    float R21 = omc * un * uy + st * ux;
    float R22 = ra + omc * un * un;
    float tms = theta - st;
    float pa  = theta - tms * q;
    float P00 = pa + tms * ux * ux;
    float P01 = tms * ux * uy - omc * un;
    float P02 = tms * ux * un + omc * uy;
    float P10 = tms * uy * ux + omc * un;
    float P11 = pa + tms * uy * uy;
    float P12 = tms * uy * un - omc * ux;
    float P20 = tms * un * ux - omc * uy;
    float P21 = tms * un * uy + omc * ux;
    float P22 = pa + tms * un * un;

    float tx = P00 * vx + P01 * vy + P02 * vz;
    float ty = P10 * vx + P11 * vy + P12 * vz;
    float tz = P20 * vx + P21 * vy + P22 * vz;

    out[3 * n + 0] = R00 * px + R01 * py + R02 * pz + tx;
    out[3 * n + 1] = R10 * px + R11 * py + R12 * pz + ty;
    out[3 * n + 2] = R20 * px + R21 * py + R22 * pz + tz;

    float dx = vdirs[3 * n + 0], dy = vdirs[3 * n + 1], dz = vdirs[3 * n + 2];
    size_t off = (size_t)3 * N;
    out[off + 3 * n + 0] = R00 * dx + R01 * dy + R02 * dz;
    out[off + 3 * n + 1] = R10 * dx + R11 * dy + R12 * dz;
    out[off + 3 * n + 2] = R20 * dx + R21 * dy + R22 * dz;
}

extern "C" void kernel_launch(void* const* d_in, const int* in_sizes, int n_in,
                              void* d_out, int out_size, void* d_ws, size_t ws_size,
                              hipStream_t stream)
{
    const float* xyz    = (const float*)d_in[0];
    const float* vd     = (const float*)d_in[1];
    // d_in[2] = transforms (unused), d_in[3] = ray_valid (unused)
    const float* planes = (const float*)d_in[4];
    const float* lines  = (const float*)d_in[5];
    const float* aabb   = (const float*)d_in[6];
    float* out = (float*)d_out;

    int N = in_sizes[0] / 3;   // 524288

    size_t needP = (size_t)3 * GRES * GRES * SC;                  // 4.72 MB (fp8)
    size_t needL = (size_t)3 * GRES * SC * sizeof(__half);        // 73.7 KB

    if (ws_size >= needP + needL) {
        uint32_t* TPq = (uint32_t*)d_ws;
        __half*   TL  = (__half*)((uint8_t*)d_ws + needP);
        tp_planes_fp8<<<3 * GRES * 3, 256, 0, stream>>>(planes, TPq);
        tp_lines<<<(3 * GRES * SC + 255) / 256, 256, 0, stream>>>(lines, TL);
        int threads = N * 2;
        bwcast_q2<<<(threads + 255) / 256, 256, 0, stream>>>(
            xyz, vd, (const uint8_t*)TPq, TL, aabb, out, N);
    } else {
        bwcast_direct<<<(N + 255) / 256, 256, 0, stream>>>(xyz, vd, planes, lines, aabb, out, N);
    }
}

// Round 6
// 192.965 us; speedup vs baseline: 4.2815x; 1.0275x over previous
//
#include <hip/hip_runtime.h>
#include <hip/hip_fp16.h>
#include <cstdint>
#include <cstddef>

#define GRES 128   // grid resolution (H = W = L)
#define SC   96    // S*C = 6*16 channels

typedef float v2f __attribute__((ext_vector_type(2)));

// Word-select of cvt_pk_f32_fp8 must be a compile-time constant at sema time;
// template parameter satisfies that.
template<bool HI>
__device__ __forceinline__ v2f cvt2(uint32_t q)
{
    return __builtin_amdgcn_cvt_pk_f32_fp8(q, HI);
}

// ---------------------------------------------------------------------------
// Fused transpose/quantize. Blocks [0,384): planes [p][sc][y][x] f32 ->
// [p][y][x][96 fp8]. One block per (p,y): float4 loads, dense uint4 stores.
// Blocks [384,528): lines [p][sc][z] -> [p][z][sc] fp16.
// ---------------------------------------------------------------------------
__global__ __launch_bounds__(256) void tp_fused(const float* __restrict__ planes,
                                                const float* __restrict__ lines,
                                                uint8_t* __restrict__ TP,
                                                __half* __restrict__ TL)
{
    int b = blockIdx.x;
    if (b < 384) {
        __shared__ float tile[SC][GRES + 1];   // 49.5 KB
        int p = b >> 7, y = b & 127;
        const float* src = planes + ((size_t)p * SC * GRES + y) * GRES;
        for (int i = threadIdx.x; i < SC * (GRES / 4); i += 256) {
            int sc = i >> 5;                   // 32 float4 per 128-row
            int x4 = (i & 31) * 4;
            float4 v = *(const float4*)(src + (size_t)sc * (GRES * GRES) + x4);
            tile[sc][x4 + 0] = v.x; tile[sc][x4 + 1] = v.y;
            tile[sc][x4 + 2] = v.z; tile[sc][x4 + 3] = v.w;
        }
        __syncthreads();
        uint4* dst = (uint4*)(TP + (size_t)b * GRES * SC);
        for (int j = threadIdx.x; j < GRES * 6; j += 256) {
            int x = j / 6, q = j - x * 6;      // q-th uint4 = channels 16q..16q+15
            int c0 = q * 16;
            uint32_t u[4];
            #pragma unroll
            for (int m = 0; m < 4; ++m) {
                uint32_t a = 0;
                a = __builtin_amdgcn_cvt_pk_fp8_f32(tile[c0 + 4 * m + 0][x],
                                                    tile[c0 + 4 * m + 1][x], a, false);
                a = __builtin_amdgcn_cvt_pk_fp8_f32(tile[c0 + 4 * m + 2][x],
                                                    tile[c0 + 4 * m + 3][x], a, true);
                u[m] = a;
            }
            dst[(size_t)x * 6 + q] = make_uint4(u[0], u[1], u[2], u[3]);
        }
    } else {
        int i = (b - 384) * 256 + threadIdx.x;
        if (i < 3 * GRES * SC) {
            int p  = i / (GRES * SC);
            int r  = i - p * (GRES * SC);
            int z  = r / SC;
            int sc = r - z * SC;
            TL[i] = __float2half(lines[((size_t)p * SC + sc) * GRES + z]);
        }
    }
}

__device__ __forceinline__ void axis_setup(float xnv, int& i0, int& i1, float& w)
{
    float f = (xnv + 1.0f) * 0.5f * (float)(GRES - 1);
    f = fminf(fmaxf(f, 0.0f), (float)(GRES - 1));
    float ff = floorf(f);
    i0 = (int)ff;
    i1 = min(i0 + 1, GRES - 1);
    w  = f - ff;
}

__device__ __forceinline__ uint32_t u4w(const uint4& q, int c)
{
    return c == 0 ? q.x : c == 1 ? q.y : c == 2 ? q.z : q.w;
}

// ---------------------------------------------------------------------------
// Main kernel: FOUR lanes per point. Lane l, iter k owns channels
// [32k + 8l, +8) -> s = 2k + (l>>1), half (l&1). fp8 planes, fp16 lines,
// packed-f32 (v_pk_fma) interp, short acc chains (acc[k][pair&1]).
// ---------------------------------------------------------------------------
__global__ __launch_bounds__(256, 4) void bwcast_q4(
    const float* __restrict__ xyz, const float* __restrict__ vdirs,
    const uint8_t* __restrict__ TP, const __half* __restrict__ TL,
    const float* __restrict__ aabb, float* __restrict__ out, int N)
{
    int t = blockIdx.x * 256 + threadIdx.x;
    int n = t >> 2;          // point index
    int l = t & 3;           // sub-lane within point
    if (n >= N) return;

    float px = xyz[3 * n + 0], py = xyz[3 * n + 1], pz = xyz[3 * n + 2];
    float xn[3];
    xn[0] = (px - aabb[0]) * (2.0f / (aabb[3] - aabb[0])) - 1.0f;
    xn[1] = (py - aabb[1]) * (2.0f / (aabb[4] - aabb[1])) - 1.0f;
    xn[2] = (pz - aabb[2]) * (2.0f / (aabb[5] - aabb[2])) - 1.0f;

    uint32_t pofs[3][4];     // byte offsets into TP (channel base = l*8)
    uint32_t lofs[3][2];     // half offsets into TL
    float W[3][4], UZ[3], WZ[3];

    #pragma unroll
    for (int p = 0; p < 3; ++p) {
        constexpr int M0[3] = {0, 0, 1};
        constexpr int M1[3] = {1, 2, 2};
        constexpr int MV[3] = {2, 1, 0};
        int x0, x1, y0, y1, z0, z1;
        float wx, wy, wz;
        axis_setup(xn[M0[p]], x0, x1, wx);
        axis_setup(xn[M1[p]], y0, y1, wy);
        axis_setup(xn[MV[p]], z0, z1, wz);
        uint32_t base = (uint32_t)l * 8u;
        pofs[p][0] = (uint32_t)((p * GRES + y0) * GRES + x0) * 96u + base;
        pofs[p][1] = (uint32_t)((p * GRES + y0) * GRES + x1) * 96u + base;
        pofs[p][2] = (uint32_t)((p * GRES + y1) * GRES + x0) * 96u + base;
        pofs[p][3] = (uint32_t)((p * GRES + y1) * GRES + x1) * 96u + base;
        lofs[p][0] = (uint32_t)((p * GRES + z0) * SC) + base;
        lofs[p][1] = (uint32_t)((p * GRES + z1) * SC) + base;
        W[p][0] = (1.f - wx) * (1.f - wy);
        W[p][1] = wx * (1.f - wy);
        W[p][2] = (1.f - wx) * wy;
        W[p][3] = wx * wy;
        UZ[p] = 1.f - wz;
        WZ[p] = wz;
    }

    v2f acc[3][2];
    #pragma unroll
    for (int k = 0; k < 3; ++k) { acc[k][0] = (v2f)(0.f); acc[k][1] = (v2f)(0.f); }

    #pragma unroll
    for (int k = 0; k < 3; ++k) {
        // ---- issue all 18 loads for this k ----
        uint2 pq[3][4];
        uint4 lq[3][2];
        #pragma unroll
        for (int p = 0; p < 3; ++p) {
            #pragma unroll
            for (int c = 0; c < 4; ++c)
                pq[p][c] = *(const uint2*)(TP + pofs[p][c] + k * 32);
            #pragma unroll
            for (int d = 0; d < 2; ++d)
                lq[p][d] = *(const uint4*)(TL + lofs[p][d] + k * 32);
        }
        // ---- consume: 8 channels = 4 v2f pairs per mode ----
        #pragma unroll
        for (int p = 0; p < 3; ++p) {
            v2f w0v = (v2f)(W[p][0]);
            v2f w1v = (v2f)(W[p][1]);
            v2f w2v = (v2f)(W[p][2]);
            v2f w3v = (v2f)(W[p][3]);
            v2f uzv = (v2f)(UZ[p]);
            v2f wzv = (v2f)(WZ[p]);

            // decode: f[corner][pair], all word-selects literal
            v2f f[4][4];
            #define DECODE_CORNER(c)                    \
                f[c][0] = cvt2<false>(pq[p][c].x);      \
                f[c][1] = cvt2<true >(pq[p][c].x);      \
                f[c][2] = cvt2<false>(pq[p][c].y);      \
                f[c][3] = cvt2<true >(pq[p][c].y);
            DECODE_CORNER(0)
            DECODE_CORNER(1)
            DECODE_CORNER(2)
            DECODE_CORNER(3)
            #undef DECODE_CORNER

            #pragma unroll
            for (int pr = 0; pr < 4; ++pr) {          // pair pr: channels 2pr,2pr+1
                uint32_t h0 = u4w(lq[p][0], pr);
                uint32_t h1 = u4w(lq[p][1], pr);
                float2 g0f = __half22float2(*reinterpret_cast<const __half2*>(&h0));
                float2 g1f = __half22float2(*reinterpret_cast<const __half2*>(&h1));
                v2f g0; g0[0] = g0f.x; g0[1] = g0f.y;
                v2f g1; g1[0] = g1f.x; g1[1] = g1f.y;
                v2f pv = f[0][pr] * w0v;
                pv = f[1][pr] * w1v + pv;
                pv = f[2][pr] * w2v + pv;
                pv = f[3][pr] * w3v + pv;
                v2f lv = g1 * wzv;
                lv = g0 * uzv + lv;
                acc[k][pr & 1] = pv * lv + acc[k][pr & 1];
            }
        }
    }

    // Horizontal sums -> part[k] (this lane's 8-channel partial of s=2k+(l>>1)).
    float part[3];
    #pragma unroll
    for (int k = 0; k < 3; ++k) {
        v2f s = acc[k][0] + acc[k][1];
        part[k] = s[0] + s[1];
    }

    // Cross-lane reduce within the 4-lane group.
    float bw[6];
    const int half_id = l >> 1;        // 0: s=2k, 1: s=2k+1
    #pragma unroll
    for (int k = 0; k < 3; ++k) {
        float v = part[k];
        v += __shfl_xor(v, 1);         // sum the two 8-ch halves of same s
        float o = __shfl_xor(v, 2);    // other parity's sum
        bw[2 * k + half_id]       = v;
        bw[2 * k + (1 - half_id)] = o;
    }

    // ---- Rodrigues / screw transform (all 4 lanes redundantly) ----
    float wxr = bw[0], wyr = bw[1], wzr = bw[2];
    float dotw = wxr * wxr + wyr * wyr + wzr * wzr;
    float theta = sqrtf(fmaxf(dotw, 1e-6f));
    float it = 1.0f / theta;
    float ux = wxr * it, uy = wyr * it, un = wzr * it;
    float vx = bw[3] * it, vy = bw[4] * it, vz = bw[5] * it;
    float st, ct;
    sincosf(theta, &st, &ct);
    float q   = ux * ux + uy * uy + un * un;   // == 1 unless theta clipped
    float omc = 1.0f - ct;
    float ra = 1.0f - omc * q;                 // skew(u)^2 = uu^T - q I
    float R00 = ra + omc * ux * ux;
    float R01 = omc * ux * uy - st * un;
    float R02 = omc * ux * un + st * uy;
    float R10 = omc * uy * ux + st * un;
    float R11 = ra + omc * uy * uy;
    float R12 = omc * uy * un - st * ux;
    float R20 = omc * un * ux - st * uy;
    float R21 = omc * un * uy + st * ux;
    float R22 = ra + omc * un * un;
    float tms = theta - st;
    float pa  = theta - tms * q;
    float P00 = pa + tms * ux * ux;
    float P01 = tms * ux * uy - omc * un;
    float P02 = tms * ux * un + omc * uy;
    float P10 = tms * uy * ux + omc * un;
    float P11 = pa + tms * uy * uy;
    float P12 = tms * uy * un - omc * ux;
    float P20 = tms * un * ux - omc * uy;
    float P21 = tms * un * uy + omc * ux;
    float P22 = pa + tms * un * un;

    float tx = P00 * vx + P01 * vy + P02 * vz;
    float ty = P10 * vx + P11 * vy + P12 * vz;
    float tz = P20 * vx + P21 * vy + P22 * vz;

    float ox = R00 * px + R01 * py + R02 * pz + tx;
    float oy = R10 * px + R11 * py + R12 * pz + ty;
    float oz = R20 * px + R21 * py + R22 * pz + tz;

    float dx = vdirs[3 * n + 0], dy = vdirs[3 * n + 1], dz = vdirs[3 * n + 2];
    float wvx = R00 * dx + R01 * dy + R02 * dz;
    float wvy = R10 * dx + R11 * dy + R12 * dz;
    float wvz = R20 * dx + R21 * dy + R22 * dz;

    // Lane l < 3 writes component l of both outputs.
    if (l < 3) {
        float o  = (l == 0) ? ox : (l == 1) ? oy : oz;
        float wv = (l == 0) ? wvx : (l == 1) ? wvy : wvz;
        out[3 * n + l] = o;
        out[(size_t)3 * N + 3 * n + l] = wv;
    }
}

// ---------------------------------------------------------------------------
// Fallback: original layouts, f32 (only if d_ws too small).
// ---------------------------------------------------------------------------
__global__ __launch_bounds__(256) void bwcast_direct(
    const float* __restrict__ xyz, const float* __restrict__ vdirs,
    const float* __restrict__ PL, const float* __restrict__ LN,
    const float* __restrict__ aabb, float* __restrict__ out, int N)
{
    int n = blockIdx.x * 256 + threadIdx.x;
    if (n >= N) return;

    float px = xyz[3 * n + 0], py = xyz[3 * n + 1], pz = xyz[3 * n + 2];
    float xn[3];
    xn[0] = (px - aabb[0]) * (2.0f / (aabb[3] - aabb[0])) - 1.0f;
    xn[1] = (py - aabb[1]) * (2.0f / (aabb[4] - aabb[1])) - 1.0f;
    xn[2] = (pz - aabb[2]) * (2.0f / (aabb[5] - aabb[2])) - 1.0f;

    float bw[6] = {0.f, 0.f, 0.f, 0.f, 0.f, 0.f};

    #pragma unroll
    for (int p = 0; p < 3; ++p) {
        constexpr int M0[3] = {0, 0, 1};
        constexpr int M1[3] = {1, 2, 2};
        constexpr int MV[3] = {2, 1, 0};
        int x0, x1, y0, y1, z0, z1;
        float wx, wy, wz;
        axis_setup(xn[M0[p]], x0, x1, wx);
        axis_setup(xn[M1[p]], y0, y1, wy);
        axis_setup(xn[MV[p]], z0, z1, wz);
        float w00 = (1.f - wx) * (1.f - wy);
        float w01 = wx * (1.f - wy);
        float w10 = (1.f - wx) * wy;
        float w11 = wx * wy;
        float uz = 1.f - wz;
        #pragma unroll
        for (int s = 0; s < 6; ++s) {
            float acc = bw[s];
            for (int c = 0; c < 16; ++c) {
                int sc = s * 16 + c;
                const float* pb = PL + (size_t)(p * SC + sc) * (GRES * GRES);
                float f00 = pb[y0 * GRES + x0];
                float f01 = pb[y0 * GRES + x1];
                float f10 = pb[y1 * GRES + x0];
                float f11 = pb[y1 * GRES + x1];
                const float* lb = LN + (size_t)(p * SC + sc) * GRES;
                float lv = fmaf(lb[z0], uz, lb[z1] * wz);
                float pv = fmaf(f00, w00, fmaf(f01, w01, fmaf(f10, w10, f11 * w11)));
                acc = fmaf(pv, lv, acc);
            }
            bw[s] = acc;
        }
    }

    float wxr = bw[0], wyr = bw[1], wzr = bw[2];
    float dotw = wxr * wxr + wyr * wyr + wzr * wzr;
    float theta = sqrtf(fmaxf(dotw, 1e-6f));
    float it = 1.0f / theta;
    float ux = wxr * it, uy = wyr * it, un = wzr * it;
    float vx = bw[3] * it, vy = bw[4] * it, vz = bw[5] * it;
    float st, ct;
    sincosf(theta, &st, &ct);
    float q   = ux * ux + uy * uy + un * un;
    float omc = 1.0f - ct;
    float ra = 1.0f - omc * q;
    float R00 = ra + omc * ux * ux;
    float R01 = omc * ux * uy - st * un;
    float R02 = omc * ux * un + st * uy;
    float R10 = omc * uy * ux + st * un;
    float R11 = ra + omc * uy * uy;
    float R12 = omc * uy * un - st * ux;
    float R20 = omc * un * ux - st * uy;
    float R21 = omc * un * uy + st * ux;
    float R22 = ra + omc * un * un;
    float tms = theta - st;
    float pa  = theta - tms * q;
    float P00 = pa + tms * ux * ux;
    float P01 = tms * ux * uy - omc * un;
    float P02 = tms * ux * un + omc * uy;
    float P10 = tms * uy * ux + omc * un;
    float P11 = pa + tms * uy * uy;
    float P12 = tms * uy * un - omc * ux;
    float P20 = tms * un * ux - omc * uy;
    float P21 = tms * un * uy + omc * ux;
    float P22 = pa + tms * un * un;

    float tx = P00 * vx + P01 * vy + P02 * vz;
    float ty = P10 * vx + P11 * vy + P12 * vz;
    float tz = P20 * vx + P21 * vy + P22 * vz;

    out[3 * n + 0] = R00 * px + R01 * py + R02 * pz + tx;
    out[3 * n + 1] = R10 * px + R11 * py + R12 * pz + ty;
    out[3 * n + 2] = R20 * px + R21 * py + R22 * pz + tz;

    float dx = vdirs[3 * n + 0], dy = vdirs[3 * n + 1], dz = vdirs[3 * n + 2];
    size_t off = (size_t)3 * N;
    out[off + 3 * n + 0] = R00 * dx + R01 * dy + R02 * dz;
    out[off + 3 * n + 1] = R10 * dx + R11 * dy + R12 * dz;
    out[off + 3 * n + 2] = R20 * dx + R21 * dy + R22 * dz;
}

extern "C" void kernel_launch(void* const* d_in, const int* in_sizes, int n_in,
                              void* d_out, int out_size, void* d_ws, size_t ws_size,
                              hipStream_t stream)
{
    const float* xyz    = (const float*)d_in[0];
    const float* vd     = (const float*)d_in[1];
    // d_in[2] = transforms (unused), d_in[3] = ray_valid (unused)
    const float* planes = (const float*)d_in[4];
    const float* lines  = (const float*)d_in[5];
    const float* aabb   = (const float*)d_in[6];
    float* out = (float*)d_out;

    int N = in_sizes[0] / 3;   // 524288

    size_t needP = (size_t)3 * GRES * GRES * SC;                  // 4.72 MB (fp8)
    size_t needL = (size_t)3 * GRES * SC * sizeof(__half);        // 73.7 KB

    if (ws_size >= needP + needL) {
        uint8_t* TP = (uint8_t*)d_ws;
        __half*  TL = (__half*)((uint8_t*)d_ws + needP);
        int tp_grid = 384 + (3 * GRES * SC + 255) / 256;          // 528
        tp_fused<<<tp_grid, 256, 0, stream>>>(planes, lines, TP, TL);
        int threads = N * 4;
        bwcast_q4<<<(threads + 255) / 256, 256, 0, stream>>>(
            xyz, vd, TP, TL, aabb, out, N);
    } else {
        bwcast_direct<<<(N + 255) / 256, 256, 0, stream>>>(xyz, vd, planes, lines, aabb, out, N);
    }
}

// Round 10
// 192.762 us; speedup vs baseline: 4.2861x; 1.0011x over previous
//
#include <hip/hip_runtime.h>
#include <hip/hip_fp16.h>
#include <cstdint>
#include <cstddef>

#define GRES 128   // grid resolution (H = W = L)
#define SC   96    // S*C = 6*16 channels

typedef float v2f __attribute__((ext_vector_type(2)));

// Word-select of cvt_pk_f32_fp8 must be a compile-time constant at sema time;
// template parameter satisfies that.
template<bool HI>
__device__ __forceinline__ v2f cvt2(uint32_t q)
{
    return __builtin_amdgcn_cvt_pk_f32_fp8(q, HI);
}

// ---------------------------------------------------------------------------
// Fused transpose/quantize. Blocks [0,384): planes [p][sc][y][x] f32 ->
// [p][y][x][96 fp8]. One block per (p,y): float4 loads, dense uint4 stores.
// Blocks [384,528): lines [p][sc][z] -> [p][z][sc] fp16.
// ---------------------------------------------------------------------------
__global__ __launch_bounds__(256) void tp_fused(const float* __restrict__ planes,
                                                const float* __restrict__ lines,
                                                uint8_t* __restrict__ TP,
                                                __half* __restrict__ TL)
{
    int b = blockIdx.x;
    if (b < 384) {
        __shared__ float tile[SC][GRES + 1];   // 49.5 KB
        int p = b >> 7, y = b & 127;
        const float* src = planes + ((size_t)p * SC * GRES + y) * GRES;
        for (int i = threadIdx.x; i < SC * (GRES / 4); i += 256) {
            int sc = i >> 5;                   // 32 float4 per 128-row
            int x4 = (i & 31) * 4;
            float4 v = *(const float4*)(src + (size_t)sc * (GRES * GRES) + x4);
            tile[sc][x4 + 0] = v.x; tile[sc][x4 + 1] = v.y;
            tile[sc][x4 + 2] = v.z; tile[sc][x4 + 3] = v.w;
        }
        __syncthreads();
        uint4* dst = (uint4*)(TP + (size_t)b * GRES * SC);
        for (int j = threadIdx.x; j < GRES * 6; j += 256) {
            int x = j / 6, q = j - x * 6;      // q-th uint4 = channels 16q..16q+15
            int c0 = q * 16;
            uint32_t u[4];
            #pragma unroll
            for (int m = 0; m < 4; ++m) {
                uint32_t a = 0;
                a = __builtin_amdgcn_cvt_pk_fp8_f32(tile[c0 + 4 * m + 0][x],
                                                    tile[c0 + 4 * m + 1][x], a, false);
                a = __builtin_amdgcn_cvt_pk_fp8_f32(tile[c0 + 4 * m + 2][x],
                                                    tile[c0 + 4 * m + 3][x], a, true);
                u[m] = a;
            }
            dst[(size_t)x * 6 + q] = make_uint4(u[0], u[1], u[2], u[3]);
        }
    } else {
        int i = (b - 384) * 256 + threadIdx.x;
        if (i < 3 * GRES * SC) {
            int p  = i / (GRES * SC);
            int r  = i - p * (GRES * SC);
            int z  = r / SC;
            int sc = r - z * SC;
            TL[i] = __float2half(lines[((size_t)p * SC + sc) * GRES + z]);
        }
    }
}

__device__ __forceinline__ void axis_setup(float xnv, int& i0, int& i1, float& w)
{
    float f = (xnv + 1.0f) * 0.5f * (float)(GRES - 1);
    f = fminf(fmaxf(f, 0.0f), (float)(GRES - 1));
    float ff = floorf(f);
    i0 = (int)ff;
    i1 = min(i0 + 1, GRES - 1);
    w  = f - ff;
}

__device__ __forceinline__ uint32_t u4w(const uint4& q, int c)
{
    return c == 0 ? q.x : c == 1 ? q.y : c == 2 ? q.z : q.w;
}

// ---------------------------------------------------------------------------
// Main kernel: FOUR lanes per point. Lane l, iter k owns channels
// [32k + 8l, +8) -> s = 2k + (l>>1), half (l&1). fp8 planes, fp16 lines,
// packed-f32 interp. Depth-2 software pipeline: k+1's 18 loads are issued
// before k is consumed (two ~48-VGPR buffers in flight).
// ---------------------------------------------------------------------------
__global__ __launch_bounds__(256, 3) void bwcast_q4(
    const float* __restrict__ xyz, const float* __restrict__ vdirs,
    const uint8_t* __restrict__ TP, const __half* __restrict__ TL,
    const float* __restrict__ aabb, float* __restrict__ out, int N)
{
    int t = blockIdx.x * 256 + threadIdx.x;
    int n = t >> 2;          // point index
    int l = t & 3;           // sub-lane within point
    if (n >= N) return;

    float px = xyz[3 * n + 0], py = xyz[3 * n + 1], pz = xyz[3 * n + 2];
    float xn[3];
    xn[0] = (px - aabb[0]) * (2.0f / (aabb[3] - aabb[0])) - 1.0f;
    xn[1] = (py - aabb[1]) * (2.0f / (aabb[4] - aabb[1])) - 1.0f;
    xn[2] = (pz - aabb[2]) * (2.0f / (aabb[5] - aabb[2])) - 1.0f;

    uint32_t pofs[3][4];     // byte offsets into TP (channel base = l*8)
    uint32_t lofs[3][2];     // half offsets into TL
    float W[3][4], UZ[3], WZ[3];

    #pragma unroll
    for (int p = 0; p < 3; ++p) {
        constexpr int M0[3] = {0, 0, 1};
        constexpr int M1[3] = {1, 2, 2};
        constexpr int MV[3] = {2, 1, 0};
        int x0, x1, y0, y1, z0, z1;
        float wx, wy, wz;
        axis_setup(xn[M0[p]], x0, x1, wx);
        axis_setup(xn[M1[p]], y0, y1, wy);
        axis_setup(xn[MV[p]], z0, z1, wz);
        uint32_t base = (uint32_t)l * 8u;
        pofs[p][0] = (uint32_t)((p * GRES + y0) * GRES + x0) * 96u + base;
        pofs[p][1] = (uint32_t)((p * GRES + y0) * GRES + x1) * 96u + base;
        pofs[p][2] = (uint32_t)((p * GRES + y1) * GRES + x0) * 96u + base;
        pofs[p][3] = (uint32_t)((p * GRES + y1) * GRES + x1) * 96u + base;
        lofs[p][0] = (uint32_t)((p * GRES + z0) * SC) + base;
        lofs[p][1] = (uint32_t)((p * GRES + z1) * SC) + base;
        W[p][0] = (1.f - wx) * (1.f - wy);
        W[p][1] = wx * (1.f - wy);
        W[p][2] = (1.f - wx) * wy;
        W[p][3] = wx * wy;
        UZ[p] = 1.f - wz;
        WZ[p] = wz;
    }

    v2f acc[3][2];
    #pragma unroll
    for (int k = 0; k < 3; ++k) { acc[k][0] = (v2f)(0.f); acc[k][1] = (v2f)(0.f); }

    auto issue = [&](int k, uint2 (&pq)[3][4], uint4 (&lq)[3][2]) {
        #pragma unroll
        for (int p = 0; p < 3; ++p) {
            #pragma unroll
            for (int c = 0; c < 4; ++c)
                pq[p][c] = *(const uint2*)(TP + pofs[p][c] + k * 32);
            #pragma unroll
            for (int d = 0; d < 2; ++d)
                lq[p][d] = *(const uint4*)(TL + lofs[p][d] + k * 32);
        }
    };

    auto consume = [&](const uint2 (&pq)[3][4], const uint4 (&lq)[3][2],
                       v2f (&ac)[2]) {
        #pragma unroll
        for (int p = 0; p < 3; ++p) {
            v2f w0v = (v2f)(W[p][0]);
            v2f w1v = (v2f)(W[p][1]);
            v2f w2v = (v2f)(W[p][2]);
            v2f w3v = (v2f)(W[p][3]);
            v2f uzv = (v2f)(UZ[p]);
            v2f wzv = (v2f)(WZ[p]);

            // decode: f[corner][pair], all word-selects literal
            v2f f[4][4];
            #define DECODE_CORNER(c)                    \
                f[c][0] = cvt2<false>(pq[p][c].x);      \
                f[c][1] = cvt2<true >(pq[p][c].x);      \
                f[c][2] = cvt2<false>(pq[p][c].y);      \
                f[c][3] = cvt2<true >(pq[p][c].y);
            DECODE_CORNER(0)
            DECODE_CORNER(1)
            DECODE_CORNER(2)
            DECODE_CORNER(3)
            #undef DECODE_CORNER

            #pragma unroll
            for (int pr = 0; pr < 4; ++pr) {          // pair pr: channels 2pr,2pr+1
                uint32_t h0 = u4w(lq[p][0], pr);
                uint32_t h1 = u4w(lq[p][1], pr);
                float2 g0f = __half22float2(*reinterpret_cast<const __half2*>(&h0));
                float2 g1f = __half22float2(*reinterpret_cast<const __half2*>(&h1));
                v2f g0; g0[0] = g0f.x; g0[1] = g0f.y;
                v2f g1; g1[0] = g1f.x; g1[1] = g1f.y;
                v2f pv = f[0][pr] * w0v;
                pv = f[1][pr] * w1v + pv;
                pv = f[2][pr] * w2v + pv;
                pv = f[3][pr] * w3v + pv;
                v2f lv = g1 * wzv;
                lv = g0 * uzv + lv;
                ac[pr & 1] = pv * lv + ac[pr & 1];
            }
        }
    };

    // Depth-2 pipeline: A=k0, B=k1 issued up front; k2 reuses A.
    uint2 pqA[3][4]; uint4 lqA[3][2];
    uint2 pqB[3][4]; uint4 lqB[3][2];
    issue(0, pqA, lqA);
    issue(1, pqB, lqB);
    consume(pqA, lqA, acc[0]);
    issue(2, pqA, lqA);
    consume(pqB, lqB, acc[1]);
    consume(pqA, lqA, acc[2]);

    // Horizontal sums -> part[k] (this lane's 8-channel partial of s=2k+(l>>1)).
    float part[3];
    #pragma unroll
    for (int k = 0; k < 3; ++k) {
        v2f s = acc[k][0] + acc[k][1];
        part[k] = s[0] + s[1];
    }

    // Cross-lane reduce within the 4-lane group.
    float bw[6];
    const int half_id = l >> 1;        // 0: s=2k, 1: s=2k+1
    #pragma unroll
    for (int k = 0; k < 3; ++k) {
        float v = part[k];
        v += __shfl_xor(v, 1);         // sum the two 8-ch halves of same s
        float o = __shfl_xor(v, 2);    // other parity's sum
        bw[2 * k + half_id]       = v;
        bw[2 * k + (1 - half_id)] = o;
    }

    // ---- Rodrigues / screw transform (all 4 lanes redundantly) ----
    float wxr = bw[0], wyr = bw[1], wzr = bw[2];
    float dotw = wxr * wxr + wyr * wyr + wzr * wzr;
    float theta = sqrtf(fmaxf(dotw, 1e-6f));
    float it = 1.0f / theta;
    float ux = wxr * it, uy = wyr * it, un = wzr * it;
    float vx = bw[3] * it, vy = bw[4] * it, vz = bw[5] * it;
    float st, ct;
    sincosf(theta, &st, &ct);
    float q   = ux * ux + uy * uy + un * un;   // == 1 unless theta clipped
    float omc = 1.0f - ct;
    float ra = 1.0f - omc * q;                 // skew(u)^2 = uu^T - q I
    float R00 = ra + omc * ux * ux;
    float R01 = omc * ux * uy - st * un;
    float R02 = omc * ux * un + st * uy;
    float R10 = omc * uy * ux + st * un;
    float R11 = ra + omc * uy * uy;
    float R12 = omc * uy * un - st * ux;
    float R20 = omc * un * ux - st * uy;
    float R21 = omc * un * uy + st * ux;
    float R22 = ra + omc * un * un;
    float tms = theta - st;
    float pa  = theta - tms * q;
    float P00 = pa + tms * ux * ux;
    float P01 = tms * ux * uy - omc * un;
    float P02 = tms * ux * un + omc * uy;
    float P10 = tms * uy * ux + omc * un;
    float P11 = pa + tms * uy * uy;
    float P12 = tms * uy * un - omc * ux;
    float P20 = tms * un * ux - omc * uy;
    float P21 = tms * un * uy + omc * ux;
    float P22 = pa + tms * un * un;

    float tx = P00 * vx + P01 * vy + P02 * vz;
    float ty = P10 * vx + P11 * vy + P12 * vz;
    float tz = P20 * vx + P21 * vy + P22 * vz;

    float ox = R00 * px + R01 * py + R02 * pz + tx;
    float oy = R10 * px + R11 * py + R12 * pz + ty;
    float oz = R20 * px + R21 * py + R22 * pz + tz;

    float dx = vdirs[3 * n + 0], dy = vdirs[3 * n + 1], dz = vdirs[3 * n + 2];
    float wvx = R00 * dx + R01 * dy + R02 * dz;
    float wvy = R10 * dx + R11 * dy + R12 * dz;
    float wvz = R20 * dx + R21 * dy + R22 * dz;

    // Lane l < 3 writes component l of both outputs.
    if (l < 3) {
        float o  = (l == 0) ? ox : (l == 1) ? oy : oz;
        float wv = (l == 0) ? wvx : (l == 1) ? wvy : wvz;
        out[3 * n + l] = o;
        out[(size_t)3 * N + 3 * n + l] = wv;
    }
}

// ---------------------------------------------------------------------------
// Fallback: original layouts, f32 (only if d_ws too small).
// ---------------------------------------------------------------------------
__global__ __launch_bounds__(256) void bwcast_direct(
    const float* __restrict__ xyz, const float* __restrict__ vdirs,
    const float* __restrict__ PL, const float* __restrict__ LN,
    const float* __restrict__ aabb, float* __restrict__ out, int N)
{
    int n = blockIdx.x * 256 + threadIdx.x;
    if (n >= N) return;

    float px = xyz[3 * n + 0], py = xyz[3 * n + 1], pz = xyz[3 * n + 2];
    float xn[3];
    xn[0] = (px - aabb[0]) * (2.0f / (aabb[3] - aabb[0])) - 1.0f;
    xn[1] = (py - aabb[1]) * (2.0f / (aabb[4] - aabb[1])) - 1.0f;
    xn[2] = (pz - aabb[2]) * (2.0f / (aabb[5] - aabb[2])) - 1.0f;

    float bw[6] = {0.f, 0.f, 0.f, 0.f, 0.f, 0.f};

    #pragma unroll
    for (int p = 0; p < 3; ++p) {
        constexpr int M0[3] = {0, 0, 1};
        constexpr int M1[3] = {1, 2, 2};
        constexpr int MV[3] = {2, 1, 0};
        int x0, x1, y0, y1, z0, z1;
        float wx, wy, wz;
        axis_setup(xn[M0[p]], x0, x1, wx);
        axis_setup(xn[M1[p]], y0, y1, wy);
        axis_setup(xn[MV[p]], z0, z1, wz);
        float w00 = (1.f - wx) * (1.f - wy);
        float w01 = wx * (1.f - wy);
        float w10 = (1.f - wx) * wy;
        float w11 = wx * wy;
        float uz = 1.f - wz;
        #pragma unroll
        for (int s = 0; s < 6; ++s) {
            float acc = bw[s];
            for (int c = 0; c < 16; ++c) {
                int sc = s * 16 + c;
                const float* pb = PL + (size_t)(p * SC + sc) * (GRES * GRES);
                float f00 = pb[y0 * GRES + x0];
                float f01 = pb[y0 * GRES + x1];
                float f10 = pb[y1 * GRES + x0];
                float f11 = pb[y1 * GRES + x1];
                const float* lb = LN + (size_t)(p * SC + sc) * GRES;
                float lv = fmaf(lb[z0], uz, lb[z1] * wz);
                float pv = fmaf(f00, w00, fmaf(f01, w01, fmaf(f10, w10, f11 * w11)));
                acc = fmaf(pv, lv, acc);
            }
            bw[s] = acc;
        }
    }

    float wxr = bw[0], wyr = bw[1], wzr = bw[2];
    float dotw = wxr * wxr + wyr * wyr + wzr * wzr;
    float theta = sqrtf(fmaxf(dotw, 1e-6f));
    float it = 1.0f / theta;
    float ux = wxr * it, uy = wyr * it, un = wzr * it;
    float vx = bw[3] * it, vy = bw[4] * it, vz = bw[5] * it;
    float st, ct;
    sincosf(theta, &st, &ct);
    float q   = ux * ux + uy * uy + un * un;
    float omc = 1.0f - ct;
    float ra = 1.0f - omc * q;
    float R00 = ra + omc * ux * ux;
    float R01 = omc * ux * uy - st * un;
    float R02 = omc * ux * un + st * uy;
    float R10 = omc * uy * ux + st * un;
    float R11 = ra + omc * uy * uy;
    float R12 = omc * uy * un - st * ux;
    float R20 = omc * un * ux - st * uy;
    float R21 = omc * un * uy + st * ux;
    float R22 = ra + omc * un * un;
    float tms = theta - st;
    float pa  = theta - tms * q;
    float P00 = pa + tms * ux * ux;
    float P01 = tms * ux * uy - omc * un;
    float P02 = tms * ux * un + omc * uy;
    float P10 = tms * uy * ux + omc * un;
    float P11 = pa + tms * uy * uy;
    float P12 = tms * uy * un - omc * ux;
    float P20 = tms * un * ux - omc * uy;
    float P21 = tms * un * uy + omc * ux;
    float P22 = pa + tms * un * un;

    float tx = P00 * vx + P01 * vy + P02 * vz;
    float ty = P10 * vx + P11 * vy + P12 * vz;
    float tz = P20 * vx + P21 * vy + P22 * vz;

    out[3 * n + 0] = R00 * px + R01 * py + R02 * pz + tx;
    out[3 * n + 1] = R10 * px + R11 * py + R12 * pz + ty;
    out[3 * n + 2] = R20 * px + R21 * py + R22 * pz + tz;

    float dx = vdirs[3 * n + 0], dy = vdirs[3 * n + 1], dz = vdirs[3 * n + 2];
    size_t off = (size_t)3 * N;
    out[off + 3 * n + 0] = R00 * dx + R01 * dy + R02 * dz;
    out[off + 3 * n + 1] = R10 * dx + R11 * dy + R12 * dz;
    out[off + 3 * n + 2] = R20 * dx + R21 * dy + R22 * dz;
}

extern "C" void kernel_launch(void* const* d_in, const int* in_sizes, int n_in,
                              void* d_out, int out_size, void* d_ws, size_t ws_size,
                              hipStream_t stream)
{
    const float* xyz    = (const float*)d_in[0];
    const float* vd     = (const float*)d_in[1];
    // d_in[2] = transforms (unused), d_in[3] = ray_valid (unused)
    const float* planes = (const float*)d_in[4];
    const float* lines  = (const float*)d_in[5];
    const float* aabb   = (const float*)d_in[6];
    float* out = (float*)d_out;

    int N = in_sizes[0] / 3;   // 524288

    size_t needP = (size_t)3 * GRES * GRES * SC;                  // 4.72 MB (fp8)
    size_t needL = (size_t)3 * GRES * SC * sizeof(__half);        // 73.7 KB

    if (ws_size >= needP + needL) {
        uint8_t* TP = (uint8_t*)d_ws;
        __half*  TL = (__half*)((uint8_t*)d_ws + needP);
        int tp_grid = 384 + (3 * GRES * SC + 255) / 256;          // 528
        tp_fused<<<tp_grid, 256, 0, stream>>>(planes, lines, TP, TL);
        int threads = N * 4;
        bwcast_q4<<<(threads + 255) / 256, 256, 0, stream>>>(
            xyz, vd, TP, TL, aabb, out, N);
    } else {
        bwcast_direct<<<(N + 255) / 256, 256, 0, stream>>>(xyz, vd, planes, lines, aabb, out, N);
    }
}

// Round 11
// 155.457 us; speedup vs baseline: 5.3146x; 1.2400x over previous
//
#include <hip/hip_runtime.h>
#include <cstdint>
#include <cstddef>

#define GRES 128   // grid resolution (H = W = L)
#define SC   96    // S*C = 6*16 channels

typedef float v2f __attribute__((ext_vector_type(2)));

// Word-select of cvt_pk_f32_fp8 must be a compile-time constant at sema time.
template<bool HI>
__device__ __forceinline__ v2f cvt2(uint32_t q)
{
    return __builtin_amdgcn_cvt_pk_f32_fp8(q, HI);
}

__device__ __forceinline__ uint32_t u4w(const uint4& q, int c)
{
    return c == 0 ? q.x : c == 1 ? q.y : c == 2 ? q.z : q.w;
}

// ---------------------------------------------------------------------------
// LDS-free transpose/quantize, one thread per (texel, 8-channel group).
//  A[texel][ch 0..64)   : 64 B records (fp8), never straddles a 128 B line
//  B[texel][ch 64..96)  : 32 B records (fp8)
//  L[(p,z)][ch 0..96)   : 128 B padded records (fp8 lines)
// Reads are x-coalesced (256 B/wave per channel row); writes are small but
// total only ~4.8 MB.
// ---------------------------------------------------------------------------
#define NPLANE_T (3 * 12 * GRES * GRES)   // 589824
#define NLINE_T  (3 * 12 * GRES)          // 4608

__global__ __launch_bounds__(256) void tp_split(const float* __restrict__ planes,
                                                const float* __restrict__ lines,
                                                uint8_t* __restrict__ A,
                                                uint8_t* __restrict__ B,
                                                uint8_t* __restrict__ L)
{
    int t = blockIdx.x * 256 + threadIdx.x;
    if (t < NPLANE_T) {
        int xy = t & (GRES * GRES - 1);      // y*128 + x
        int pg = t >> 14;                    // p*12 + g
        int g  = pg % 12;
        int p  = pg / 12;
        int ch0 = 8 * g;                     // 0..88
        const float* src = planes + ((size_t)(p * SC + ch0) * (GRES * GRES)) + xy;
        float v[8];
        #pragma unroll
        for (int i = 0; i < 8; ++i) v[i] = src[(size_t)i * (GRES * GRES)];
        uint32_t w0 = 0, w1 = 0;
        w0 = __builtin_amdgcn_cvt_pk_fp8_f32(v[0], v[1], w0, false);
        w0 = __builtin_amdgcn_cvt_pk_fp8_f32(v[2], v[3], w0, true);
        w1 = __builtin_amdgcn_cvt_pk_fp8_f32(v[4], v[5], w1, false);
        w1 = __builtin_amdgcn_cvt_pk_fp8_f32(v[6], v[7], w1, true);
        uint2 pkt = make_uint2(w0, w1);
        int texel = (p << 14) + xy;          // (p*128+y)*128 + x
        if (g < 8)
            *(uint2*)(A + (size_t)texel * 64 + 8 * g) = pkt;
        else
            *(uint2*)(B + (size_t)texel * 32 + 8 * (g - 8)) = pkt;
    } else if (t < NPLANE_T + NLINE_T) {
        int r = t - NPLANE_T;
        int z  = r & (GRES - 1);
        int pg = r >> 7;
        int g  = pg % 12;
        int p  = pg / 12;
        int ch0 = 8 * g;
        const float* src = lines + ((size_t)(p * SC + ch0) * GRES) + z;
        float v[8];
        #pragma unroll
        for (int i = 0; i < 8; ++i) v[i] = src[(size_t)i * GRES];
        uint32_t w0 = 0, w1 = 0;
        w0 = __builtin_amdgcn_cvt_pk_fp8_f32(v[0], v[1], w0, false);
        w0 = __builtin_amdgcn_cvt_pk_fp8_f32(v[2], v[3], w0, true);
        w1 = __builtin_amdgcn_cvt_pk_fp8_f32(v[4], v[5], w1, false);
        w1 = __builtin_amdgcn_cvt_pk_fp8_f32(v[6], v[7], w1, true);
        *(uint2*)(L + (size_t)(p * GRES + z) * 128 + 8 * g) = make_uint2(w0, w1);
    }
}

__device__ __forceinline__ void axis_setup(float xnv, int& i0, int& i1, float& w)
{
    float f = (xnv + 1.0f) * 0.5f * (float)(GRES - 1);
    f = fminf(fmaxf(f, 0.0f), (float)(GRES - 1));
    float ff = floorf(f);
    i0 = (int)ff;
    i1 = min(i0 + 1, GRES - 1);
    w  = f - ff;
}

// ---------------------------------------------------------------------------
// Main kernel: FOUR lanes per point. Lane l owns s-block l fully (ch 16l..16l+16,
// via one uint4 from A per corner) plus half of s-block 4+(l>>1) (ch 64+8l..+8,
// via one uint2 from B). Lines fp8, L1-resident. Reduce: 7 shfl ops.
// ---------------------------------------------------------------------------
__global__ __launch_bounds__(256) void bwcast_s4(
    const float* __restrict__ xyz, const float* __restrict__ vdirs,
    const uint8_t* __restrict__ A, const uint8_t* __restrict__ B,
    const uint8_t* __restrict__ L, const float* __restrict__ aabb,
    float* __restrict__ out, int N)
{
    int t = blockIdx.x * 256 + threadIdx.x;
    int n = t >> 2;          // point index
    int l = t & 3;           // sub-lane within point
    if (n >= N) return;
    int lane = threadIdx.x & 63;

    float px = xyz[3 * n + 0], py = xyz[3 * n + 1], pz = xyz[3 * n + 2];
    float xn[3];
    xn[0] = (px - aabb[0]) * (2.0f / (aabb[3] - aabb[0])) - 1.0f;
    xn[1] = (py - aabb[1]) * (2.0f / (aabb[4] - aabb[1])) - 1.0f;
    xn[2] = (pz - aabb[2]) * (2.0f / (aabb[5] - aabb[2])) - 1.0f;

    uint32_t aoff[3][4], boff[3][4];   // byte offsets into A / B
    uint32_t lo4[3][2], lo2[3][2];     // byte offsets into L (uint4 part, uint2 part)
    float W[3][4], UZ[3], WZ[3];

    #pragma unroll
    for (int p = 0; p < 3; ++p) {
        constexpr int M0[3] = {0, 0, 1};
        constexpr int M1[3] = {1, 2, 2};
        constexpr int MV[3] = {2, 1, 0};
        int x0, x1, y0, y1, z0, z1;
        float wx, wy, wz;
        axis_setup(xn[M0[p]], x0, x1, wx);
        axis_setup(xn[M1[p]], y0, y1, wy);
        axis_setup(xn[MV[p]], z0, z1, wz);
        uint32_t t00 = (uint32_t)((p * GRES + y0) * GRES + x0);
        uint32_t t01 = (uint32_t)((p * GRES + y0) * GRES + x1);
        uint32_t t10 = (uint32_t)((p * GRES + y1) * GRES + x0);
        uint32_t t11 = (uint32_t)((p * GRES + y1) * GRES + x1);
        uint32_t a16 = (uint32_t)l * 16u, b8 = (uint32_t)l * 8u;
        aoff[p][0] = t00 * 64u + a16;  boff[p][0] = t00 * 32u + b8;
        aoff[p][1] = t01 * 64u + a16;  boff[p][1] = t01 * 32u + b8;
        aoff[p][2] = t10 * 64u + a16;  boff[p][2] = t10 * 32u + b8;
        aoff[p][3] = t11 * 64u + a16;  boff[p][3] = t11 * 32u + b8;
        uint32_t r0 = (uint32_t)(p * GRES + z0) * 128u;
        uint32_t r1 = (uint32_t)(p * GRES + z1) * 128u;
        lo4[p][0] = r0 + a16;          lo2[p][0] = r0 + 64u + b8;
        lo4[p][1] = r1 + a16;          lo2[p][1] = r1 + 64u + b8;
        W[p][0] = (1.f - wx) * (1.f - wy);
        W[p][1] = wx * (1.f - wy);
        W[p][2] = (1.f - wx) * wy;
        W[p][3] = wx * wy;
        UZ[p] = 1.f - wz;
        WZ[p] = wz;
    }

    v2f aLE = (v2f)(0.f), aLO = (v2f)(0.f);   // lo (16-ch) even/odd pair accs
    v2f aHE = (v2f)(0.f), aHO = (v2f)(0.f);   // hi (8-ch) even/odd pair accs

    #pragma unroll
    for (int p = 0; p < 3; ++p) {
        // ---- issue this mode's 12 loads ----
        uint4 a4[4]; uint2 b2[4];
        #pragma unroll
        for (int c = 0; c < 4; ++c) {
            a4[c] = *(const uint4*)(A + aoff[p][c]);
            b2[c] = *(const uint2*)(B + boff[p][c]);
        }
        uint4 l4[2]; uint2 l2[2];
        #pragma unroll
        for (int d = 0; d < 2; ++d) {
            l4[d] = *(const uint4*)(L + lo4[p][d]);
            l2[d] = *(const uint2*)(L + lo2[p][d]);
        }
        v2f w0v = (v2f)(W[p][0]);
        v2f w1v = (v2f)(W[p][1]);
        v2f w2v = (v2f)(W[p][2]);
        v2f w3v = (v2f)(W[p][3]);
        v2f uzv = (v2f)(UZ[p]);
        v2f wzv = (v2f)(WZ[p]);

        // ---- lo: 4 words x 4 fp8 = 16 channels ----
        #pragma unroll
        for (int k = 0; k < 4; ++k) {
            uint32_t wa0 = u4w(a4[0], k), wa1 = u4w(a4[1], k);
            uint32_t wa2 = u4w(a4[2], k), wa3 = u4w(a4[3], k);
            uint32_t wl0 = u4w(l4[0], k), wl1 = u4w(l4[1], k);
            v2f pv = cvt2<false>(wa0) * w0v;
            pv = cvt2<false>(wa1) * w1v + pv;
            pv = cvt2<false>(wa2) * w2v + pv;
            pv = cvt2<false>(wa3) * w3v + pv;
            v2f lv = cvt2<false>(wl1) * wzv;
            lv = cvt2<false>(wl0) * uzv + lv;
            aLE = pv * lv + aLE;
            v2f pu = cvt2<true>(wa0) * w0v;
            pu = cvt2<true>(wa1) * w1v + pu;
            pu = cvt2<true>(wa2) * w2v + pu;
            pu = cvt2<true>(wa3) * w3v + pu;
            v2f lu = cvt2<true>(wl1) * wzv;
            lu = cvt2<true>(wl0) * uzv + lu;
            aLO = pu * lu + aLO;
        }
        // ---- hi: 2 words x 4 fp8 = 8 channels ----
        #pragma unroll
        for (int k = 0; k < 2; ++k) {
            uint32_t wb0 = k ? b2[0].y : b2[0].x;
            uint32_t wb1 = k ? b2[1].y : b2[1].x;
            uint32_t wb2 = k ? b2[2].y : b2[2].x;
            uint32_t wb3 = k ? b2[3].y : b2[3].x;
            uint32_t wl0 = k ? l2[0].y : l2[0].x;
            uint32_t wl1 = k ? l2[1].y : l2[1].x;
            v2f pv = cvt2<false>(wb0) * w0v;
            pv = cvt2<false>(wb1) * w1v + pv;
            pv = cvt2<false>(wb2) * w2v + pv;
            pv = cvt2<false>(wb3) * w3v + pv;
            v2f lv = cvt2<false>(wl1) * wzv;
            lv = cvt2<false>(wl0) * uzv + lv;
            aHE = pv * lv + aHE;
            v2f pu = cvt2<true>(wb0) * w0v;
            pu = cvt2<true>(wb1) * w1v + pu;
            pu = cvt2<true>(wb2) * w2v + pu;
            pu = cvt2<true>(wb3) * w3v + pu;
            v2f lu = cvt2<true>(wl1) * wzv;
            lu = cvt2<true>(wl0) * uzv + lu;
            aHO = pu * lu + aHO;
        }
    }

    v2f sl = aLE + aLO;
    float part_lo = sl[0] + sl[1];       // full bw of s = l
    v2f sh = aHE + aHO;
    float part_hi = sh[0] + sh[1];       // half of s = 4 + (l>>1)

    // ---- reduce / broadcast within 4-lane group ----
    int base = lane & ~3;
    float bw[6];
    bw[0] = __shfl(part_lo, base + 0);
    bw[1] = __shfl(part_lo, base + 1);
    bw[2] = __shfl(part_lo, base + 2);
    bw[3] = __shfl(part_lo, base + 3);
    float ph2 = part_hi + __shfl_xor(part_hi, 1);
    bw[4] = __shfl(ph2, base + 0);
    bw[5] = __shfl(ph2, base + 2);

    // ---- Rodrigues / screw transform (all 4 lanes redundantly) ----
    float wxr = bw[0], wyr = bw[1], wzr = bw[2];
    float dotw = wxr * wxr + wyr * wyr + wzr * wzr;
    float theta = sqrtf(fmaxf(dotw, 1e-6f));
    float it = 1.0f / theta;
    float ux = wxr * it, uy = wyr * it, un = wzr * it;
    float vx = bw[3] * it, vy = bw[4] * it, vz = bw[5] * it;
    float st, ct;
    sincosf(theta, &st, &ct);
    float q   = ux * ux + uy * uy + un * un;   // == 1 unless theta clipped
    float omc = 1.0f - ct;
    float ra = 1.0f - omc * q;                 // skew(u)^2 = uu^T - q I
    float R00 = ra + omc * ux * ux;
    float R01 = omc * ux * uy - st * un;
    float R02 = omc * ux * un + st * uy;
    float R10 = omc * uy * ux + st * un;
    float R11 = ra + omc * uy * uy;
    float R12 = omc * uy * un - st * ux;
    float R20 = omc * un * ux - st * uy;
    float R21 = omc * un * uy + st * ux;
    float R22 = ra + omc * un * un;
    float tms = theta - st;
    float pa  = theta - tms * q;
    float P00 = pa + tms * ux * ux;
    float P01 = tms * ux * uy - omc * un;
    float P02 = tms * ux * un + omc * uy;
    float P10 = tms * uy * ux + omc * un;
    float P11 = pa + tms * uy * uy;
    float P12 = tms * uy * un - omc * ux;
    float P20 = tms * un * ux - omc * uy;
    float P21 = tms * un * uy + omc * ux;
    float P22 = pa + tms * un * un;

    float tx = P00 * vx + P01 * vy + P02 * vz;
    float ty = P10 * vx + P11 * vy + P12 * vz;
    float tz = P20 * vx + P21 * vy + P22 * vz;

    float ox = R00 * px + R01 * py + R02 * pz + tx;
    float oy = R10 * px + R11 * py + R12 * pz + ty;
    float oz = R20 * px + R21 * py + R22 * pz + tz;

    float dx = vdirs[3 * n + 0], dy = vdirs[3 * n + 1], dz = vdirs[3 * n + 2];
    float wvx = R00 * dx + R01 * dy + R02 * dz;
    float wvy = R10 * dx + R11 * dy + R12 * dz;
    float wvz = R20 * dx + R21 * dy + R22 * dz;

    if (l < 3) {
        float o  = (l == 0) ? ox : (l == 1) ? oy : oz;
        float wv = (l == 0) ? wvx : (l == 1) ? wvy : wvz;
        out[3 * n + l] = o;
        out[(size_t)3 * N + 3 * n + l] = wv;
    }
}

// ---------------------------------------------------------------------------
// Fallback: original layouts, f32 (only if d_ws too small).
// ---------------------------------------------------------------------------
__global__ __launch_bounds__(256) void bwcast_direct(
    const float* __restrict__ xyz, const float* __restrict__ vdirs,
    const float* __restrict__ PL, const float* __restrict__ LN,
    const float* __restrict__ aabb, float* __restrict__ out, int N)
{
    int n = blockIdx.x * 256 + threadIdx.x;
    if (n >= N) return;

    float px = xyz[3 * n + 0], py = xyz[3 * n + 1], pz = xyz[3 * n + 2];
    float xn[3];
    xn[0] = (px - aabb[0]) * (2.0f / (aabb[3] - aabb[0])) - 1.0f;
    xn[1] = (py - aabb[1]) * (2.0f / (aabb[4] - aabb[1])) - 1.0f;
    xn[2] = (pz - aabb[2]) * (2.0f / (aabb[5] - aabb[2])) - 1.0f;

    float bw[6] = {0.f, 0.f, 0.f, 0.f, 0.f, 0.f};

    #pragma unroll
    for (int p = 0; p < 3; ++p) {
        constexpr int M0[3] = {0, 0, 1};
        constexpr int M1[3] = {1, 2, 2};
        constexpr int MV[3] = {2, 1, 0};
        int x0, x1, y0, y1, z0, z1;
        float wx, wy, wz;
        axis_setup(xn[M0[p]], x0, x1, wx);
        axis_setup(xn[M1[p]], y0, y1, wy);
        axis_setup(xn[MV[p]], z0, z1, wz);
        float w00 = (1.f - wx) * (1.f - wy);
        float w01 = wx * (1.f - wy);
        float w10 = (1.f - wx) * wy;
        float w11 = wx * wy;
        float uz = 1.f - wz;
        #pragma unroll
        for (int s = 0; s < 6; ++s) {
            float acc = bw[s];
            for (int c = 0; c < 16; ++c) {
                int sc = s * 16 + c;
                const float* pb = PL + (size_t)(p * SC + sc) * (GRES * GRES);
                float f00 = pb[y0 * GRES + x0];
                float f01 = pb[y0 * GRES + x1];
                float f10 = pb[y1 * GRES + x0];
                float f11 = pb[y1 * GRES + x1];
                const float* lb = LN + (size_t)(p * SC + sc) * GRES;
                float lv = fmaf(lb[z0], uz, lb[z1] * wz);
                float pv = fmaf(f00, w00, fmaf(f01, w01, fmaf(f10, w10, f11 * w11)));
                acc = fmaf(pv, lv, acc);
            }
            bw[s] = acc;
        }
    }

    float wxr = bw[0], wyr = bw[1], wzr = bw[2];
    float dotw = wxr * wxr + wyr * wyr + wzr * wzr;
    float theta = sqrtf(fmaxf(dotw, 1e-6f));
    float it = 1.0f / theta;
    float ux = wxr * it, uy = wyr * it, un = wzr * it;
    float vx = bw[3] * it, vy = bw[4] * it, vz = bw[5] * it;
    float st, ct;
    sincosf(theta, &st, &ct);
    float q   = ux * ux + uy * uy + un * un;
    float omc = 1.0f - ct;
    float ra = 1.0f - omc * q;
    float R00 = ra + omc * ux * ux;
    float R01 = omc * ux * uy - st * un;
    float R02 = omc * ux * un + st * uy;
    float R10 = omc * uy * ux + st * un;
    float R11 = ra + omc * uy * uy;
    float R12 = omc * uy * un - st * ux;
    float R20 = omc * un * ux - st * uy;
    float R21 = omc * un * uy + st * ux;
    float R22 = ra + omc * un * un;
    float tms = theta - st;
    float pa  = theta - tms * q;
    float P00 = pa + tms * ux * ux;
    float P01 = tms * ux * uy - omc * un;
    float P02 = tms * ux * un + omc * uy;
    float P10 = tms * uy * ux + omc * un;
    float P11 = pa + tms * uy * uy;
    float P12 = tms * uy * un - omc * ux;
    float P20 = tms * un * ux - omc * uy;
    float P21 = tms * un * uy + omc * ux;
    float P22 = pa + tms * un * un;

    float tx = P00 * vx + P01 * vy + P02 * vz;
    float ty = P10 * vx + P11 * vy + P12 * vz;
    float tz = P20 * vx + P21 * vy + P22 * vz;

    out[3 * n + 0] = R00 * px + R01 * py + R02 * pz + tx;
    out[3 * n + 1] = R10 * px + R11 * py + R12 * pz + ty;
    out[3 * n + 2] = R20 * px + R21 * py + R22 * pz + tz;

    float dx = vdirs[3 * n + 0], dy = vdirs[3 * n + 1], dz = vdirs[3 * n + 2];
    size_t off = (size_t)3 * N;
    out[off + 3 * n + 0] = R00 * dx + R01 * dy + R02 * dz;
    out[off + 3 * n + 1] = R10 * dx + R11 * dy + R12 * dz;
    out[off + 3 * n + 2] = R20 * dx + R21 * dy + R22 * dz;
}

extern "C" void kernel_launch(void* const* d_in, const int* in_sizes, int n_in,
                              void* d_out, int out_size, void* d_ws, size_t ws_size,
                              hipStream_t stream)
{
    const float* xyz    = (const float*)d_in[0];
    const float* vd     = (const float*)d_in[1];
    // d_in[2] = transforms (unused), d_in[3] = ray_valid (unused)
    const float* planes = (const float*)d_in[4];
    const float* lines  = (const float*)d_in[5];
    const float* aabb   = (const float*)d_in[6];
    float* out = (float*)d_out;

    int N = in_sizes[0] / 3;   // 524288

    size_t szA = (size_t)3 * GRES * GRES * 64;   // 3.15 MB
    size_t szB = (size_t)3 * GRES * GRES * 32;   // 1.57 MB
    size_t szL = (size_t)3 * GRES * 128;         // 49 KB

    if (ws_size >= szA + szB + szL) {
        uint8_t* A = (uint8_t*)d_ws;
        uint8_t* Bp = A + szA;
        uint8_t* L = Bp + szB;
        int tp_threads = NPLANE_T + NLINE_T;
        tp_split<<<(tp_threads + 255) / 256, 256, 0, stream>>>(planes, lines, A, Bp, L);
        int threads = N * 4;
        bwcast_s4<<<(threads + 255) / 256, 256, 0, stream>>>(
            xyz, vd, A, Bp, L, aabb, out, N);
    } else {
        bwcast_direct<<<(N + 255) / 256, 256, 0, stream>>>(xyz, vd, planes, lines, aabb, out, N);
    }
}